// Round 2
// baseline (287.911 us; speedup 1.0000x reference)
//
#include <hip/hip_runtime.h>
#include <math.h>

// ---------------------------------------------------------------------------
// CrossViewAttention — R6: mega kernel v2 — barrier-free L2-direct GEMMs.
// prep (unchanged) -> KV GEMMs -> mega chunk kernel v2 -> out_kernel.
// B=1, C=256, M=4096, W=128, H=32, BLOCKS=2, HEADS=8, DH=32
// ---------------------------------------------------------------------------

#define C_DIM 256
#define M_DIM 4096
#define W_DIM 128
#define H_DIM 32
#define ATT_SCALE 0.17677669529663687f  // 1/sqrt(32)

typedef __attribute__((ext_vector_type(8))) short short8;
typedef __attribute__((ext_vector_type(4))) short short4v;
typedef __attribute__((ext_vector_type(4))) float floatx4;

__device__ __forceinline__ unsigned short f2bf(float f) {
    unsigned u = __float_as_uint(f);
    unsigned r = (u + 0x7fffu + ((u >> 16) & 1u)) >> 16;
    return (unsigned short)r;
}
__device__ __forceinline__ float gelu_exact(float x) {
    return 0.5f * x * (1.0f + erff(x * 0.70710678118654752f));
}

// ======================= mega prep kernel (unchanged) ======================
struct PrepArgs {
    const float* grd2sat; float* xcur;
    const float* grd_x;   float* yhat;
    const float* u; int* perm; int4* chunks; int* nchunks;
    const float* win[12]; unsigned short* wout[12]; const float* wlnw[12];
    int wR[12], wC[12], wbase[13];
    const float* fW[10]; const float* flnb[10]; const float* fbase[10];
    float* fout[10];
    int fN[10], fwcol[10], focol[10];
};

__global__ __launch_bounds__(256) void prep_kernel(PrepArgs a) {
    __shared__ float smemf[9024];
    int b = blockIdx.x, t = threadIdx.x;
    if (b < 256) {
        float (*tile)[65] = (float(*)[65])smemf;
        int m0 = (b & 63) << 6, c0 = (b >> 6) << 6;
        for (int it = 0; it < 16; ++it) {
            int idx = it * 256 + t;
            int co = idx >> 6, mo = idx & 63;
            tile[co][mo] = a.grd2sat[(size_t)(c0 + co) * M_DIM + m0 + mo];
        }
        __syncthreads();
        for (int it = 0; it < 16; ++it) {
            int idx = it * 256 + t;
            int mo = idx >> 6, co = idx & 63;
            a.xcur[(size_t)(m0 + mo) * C_DIM + c0 + co] = tile[co][mo];
        }
    } else if (b < 384) {
        int idx = b - 256;
        int h = idx & 31, w0 = (idx >> 5) << 5;
        float (*tile)[33] = (float(*)[33])smemf;
        float (*ps)[32] = (float(*)[32])(smemf + 8448);
        float (*pss)[32] = (float(*)[32])(smemf + 8704);
        float* mu_s = smemf + 8960;
        float* rs_s = smemf + 8992;
        int wo = t & 31, cb = t >> 5;
        for (int it = 0; it < 32; ++it) {
            int c = it * 8 + cb;
            tile[c][wo] = a.grd_x[(size_t)c * (H_DIM * W_DIM) + h * W_DIM + w0 + wo];
        }
        __syncthreads();
        {
            int w = t & 31, part = t >> 5;
            float s = 0.f, ss = 0.f;
            for (int c = part * 32; c < part * 32 + 32; ++c) {
                float x = tile[c][w];
                s += x; ss += x * x;
            }
            ps[part][w] = s; pss[part][w] = ss;
        }
        __syncthreads();
        if (t < 32) {
            float s = 0.f, ss = 0.f;
            for (int p = 0; p < 8; ++p) { s += ps[p][t]; ss += pss[p][t]; }
            float mu = s * (1.f / 256.f);
            float var = ss * (1.f / 256.f) - mu * mu;
            mu_s[t] = mu;
            rs_s[t] = rsqrtf(var + 1e-5f);
        }
        __syncthreads();
        for (int jj = 0; jj < 32; ++jj) {
            float mu = mu_s[jj], rs = rs_s[jj];
            a.yhat[((size_t)(w0 + jj) * H_DIM + h) * C_DIM + t] =
                (tile[t][jj] - mu) * rs;
        }
    } else if (b < 1408) {
        int wI = b - 384;
        int e = 0;
        while (wI >= a.wbase[e + 1]) ++e;
        int tl = wI - a.wbase[e];
        int tilesC = a.wC[e] >> 5;
        int tr = tl / tilesC, tc = tl - tr * tilesC;
        int r0 = tr << 5, c0 = tc << 5;
        const float* in = a.win[e];
        unsigned short* out = a.wout[e];
        const float* lnw = a.wlnw[e];
        int R = a.wR[e], Cc = a.wC[e];
        float (*tile)[33] = (float(*)[33])smemf;
        int rl = t >> 3, cq = (t & 7) << 2;
        float4 v = *(const float4*)&in[(size_t)(r0 + rl) * Cc + c0 + cq];
        if (lnw) {
            float s = lnw[r0 + rl];
            v.x *= s; v.y *= s; v.z *= s; v.w *= s;
        }
        tile[rl][cq + 0] = v.x;
        tile[rl][cq + 1] = v.y;
        tile[rl][cq + 2] = v.z;
        tile[rl][cq + 3] = v.w;
        __syncthreads();
        int cl = t >> 3, rq = (t & 7) << 2;
        ushort4 o;
        o.x = f2bf(tile[rq + 0][cl]);
        o.y = f2bf(tile[rq + 1][cl]);
        o.z = f2bf(tile[rq + 2][cl]);
        o.w = f2bf(tile[rq + 3][cl]);
        *(ushort4*)&out[(size_t)(c0 + cl) * R + r0 + rq] = o;
    } else if (b < 1418) {
        int jj = b - 1408;
        int N = a.fN[jj];
        int wcol = a.fwcol[jj] + t;
        const float* W = a.fW[jj];
        const float* lb = a.flnb[jj];
        float s = a.fbase[jj] ? a.fbase[jj][wcol] : 0.f;
        for (int k = 0; k < 256; ++k) s += lb[k] * W[(size_t)k * N + wcol];
        a.fout[jj][a.focol[jj] + t] = s;
    } else {
        int* hist = (int*)smemf;
        int* cur = (int*)smemf + 128;
        unsigned short* wlb = (unsigned short*)((int*)smemf + 256);
        if (t < 128) hist[t] = 0;
        __syncthreads();
        for (int it = 0; it < 16; ++it) {
            int m = it * 256 + t;
            int wl = (int)floorf(a.u[m]);
            wl = max(0, min(wl, 126));
            wlb[m] = (unsigned short)wl;
            atomicAdd(&hist[wl], 1);
        }
        __syncthreads();
        if (t == 0) {
            int run = 0, nc = 0;
            for (int bkt = 0; bkt < 127; ++bkt) {
                int c = hist[bkt];
                cur[bkt] = run;
                int q0 = run;
                while (c > 0) {
                    int take = min(c, 32);
                    a.chunks[nc] = make_int4(bkt, q0, take, 0);
                    ++nc; q0 += take; c -= take;
                }
                run += hist[bkt];
            }
            *a.nchunks = nc;
        }
        __syncthreads();
        for (int it = 0; it < 16; ++it) {
            int m = it * 256 + t;
            int wl = wlb[m];
            int pos = atomicAdd(&cur[wl], 1);
            a.perm[pos] = m;
        }
    }
}

// ======================= templated MFMA GEMM (KV only) =====================
struct GJ {
    const void* A; const unsigned short* Bt;
    const float* bias; const float* aw; const float* ab;
    const float* rw; const float* rb; const float* res;
    float* wrz; void* out; unsigned short* out2;
    int K, N;
};

template <int LN, int EPI, int OUTM, bool WRZ, bool ABF16>
__device__ __forceinline__ void gemm_core(const GJ& j, short (*As)[264],
                                          short (*Bs)[264], int bm, int by) {
    int t = threadIdx.x;
    int bn = by << 6;
    int wv = t >> 6, lane = t & 63;
    int mt = wv & 1, nt0 = (wv >> 1) << 1;
    int quad = lane >> 4, l16 = lane & 15;
    floatx4 acc0 = {0.f, 0.f, 0.f, 0.f};
    floatx4 acc1 = {0.f, 0.f, 0.f, 0.f};
    const int K = j.K;
    for (int kc = 0; kc < K; kc += 256) {
        if (kc) __syncthreads();
        {
            int ar = t >> 3, cq = (t & 7) << 2;
            const float* ap = (const float*)j.A + (size_t)(bm + ar) * K + kc + cq;
            float4 v[8];
#pragma unroll
            for (int g = 0; g < 8; ++g) v[g] = *(const float4*)(ap + g * 32);
#pragma unroll
            for (int g = 0; g < 8; ++g) {
                short4v o;
                o[0] = (short)f2bf(v[g].x);
                o[1] = (short)f2bf(v[g].y);
                o[2] = (short)f2bf(v[g].z);
                o[3] = (short)f2bf(v[g].w);
                *(short4v*)&As[ar][cq + g * 32] = o;
            }
        }
        {
            int br = t >> 2, cq2 = (t & 3) << 3;
            const unsigned short* bp = j.Bt + (size_t)(bn + br) * K + kc + cq2;
#pragma unroll
            for (int g = 0; g < 8; ++g)
                *(short8*)&Bs[br][cq2 + g * 32] = *(const short8*)(bp + g * 32);
        }
        __syncthreads();
#pragma unroll
        for (int k0 = 0; k0 < 8; ++k0) {
            short8 aa = *(const short8*)&As[(mt << 4) + l16][(k0 << 5) + (quad << 3)];
            short8 b0 = *(const short8*)&Bs[(nt0 << 4) + l16][(k0 << 5) + (quad << 3)];
            short8 b1 =
                *(const short8*)&Bs[((nt0 + 1) << 4) + l16][(k0 << 5) + (quad << 3)];
            acc0 = __builtin_amdgcn_mfma_f32_16x16x32_bf16(aa, b0, acc0, 0, 0, 0);
            acc1 = __builtin_amdgcn_mfma_f32_16x16x32_bf16(aa, b1, acc1, 0, 0, 0);
        }
    }
#pragma unroll
    for (int jj = 0; jj < 2; ++jj) {
        const floatx4 accv = jj ? acc1 : acc0;
        int col = bn + ((nt0 + jj) << 4) + l16;
        float bv = j.bias ? j.bias[col] : 0.f;
#pragma unroll
        for (int r = 0; r < 4; ++r) {
            int row = bm + (mt << 4) + (quad << 2) + r;
            float v = accv[r] + bv;
            if (col < 256)
                ((unsigned short*)j.out)[(size_t)row * 256 + col] = f2bf(v);
            else
                j.out2[(size_t)(col - 256) * M_DIM + row] = f2bf(v);
        }
    }
}

// K/V for both transformer blocks: grid (128, 16)
__global__ __launch_bounds__(256) void kv_kernel(GJ j0, GJ j1) {
    __shared__ short As[32][264];
    __shared__ short Bs[64][264];
    int bm = blockIdx.x << 5;
    if ((int)blockIdx.y < 8)
        gemm_core<0, 0, 2, false, false>(j0, As, Bs, bm, blockIdx.y);
    else
        gemm_core<0, 0, 2, false, false>(j1, As, Bs, bm, blockIdx.y - 8);
}

// ======================= mega chunk kernel v2 ==============================
struct MegaArgs {
    const float* xcur;
    const int* perm; const int4* chunks; const int* nchunks;
    float* xfinal;
    const unsigned short* Wq[2]; const unsigned short* Wp[2];
    const unsigned short* Wm1[2]; const unsigned short* Wm2[2];
    const unsigned short* Ktb[2]; const unsigned short* Vtb[2];
    const float* qb[2]; const float* m1b[2];
    const float* bpj[2]; const float* bm2v[2];
    const float* pw[2]; const float* pb[2];
    const float* aw; const float* ab;  // ln_post[0] for layer-1 LN2
};

// Barrier-free merged GEMM: 32 rows (LDS bf16 A, pitch lda) x 128 cols/wave.
// Each wave: 8 col-tiles, A frags from LDS, B frags straight from L2.
__device__ __forceinline__ void mgemm8(const short* As, int lda,
                                       const unsigned short* Bt, int Kstride,
                                       int kcB, int laneRow, int colbase,
                                       int quad, int l16, floatx4 acc[8]) {
    const short* ap = As + (size_t)laneRow * lda + (quad << 3);
    const unsigned short* bp =
        Bt + (size_t)(colbase + l16) * Kstride + kcB + (quad << 3);
#pragma unroll
    for (int k0 = 0; k0 < 8; ++k0) {
        short8 aa = *(const short8*)(ap + (k0 << 5));
#pragma unroll
        for (int i = 0; i < 8; ++i) {
            short8 bb =
                *(const short8*)(bp + (size_t)(i << 4) * Kstride + (k0 << 5));
            acc[i] = __builtin_amdgcn_mfma_f32_16x16x32_bf16(aa, bb, acc[i], 0, 0, 0);
        }
    }
}

// LDS layout (bytes):
//  [0,      16896)  XH short[32][264]   (stage1->Q)   / HH0 (m1 half0)
//  [16896,  33792)  QR short[32][264]   (Q->attn)     / HH1 (m1 half1)
//  [33792,  50688)  ZH short[32][264]   (LNz->m1)
//  [50688,  67584)  AR short[32][264]   (attn->proj)
//  [67584, 100864)  Zf float[32][260]   (proj residual; x' in-place after m2)
//  [100864,118272)  SS float[2][32][68] (scores, 2 heads)
//  [118272,127488)  PB short[2][32][72] (softmax P, 2 heads)
//  [127488,127616)  gperm int[32]
__global__ __launch_bounds__(256, 1) void mega_kernel(MegaArgs a) {
    __shared__ __align__(16) char smem[127616];
    short (*XH)[264] = (short(*)[264])(smem);
    short (*QR)[264] = (short(*)[264])(smem + 16896);
    short (*ZH)[264] = (short(*)[264])(smem + 33792);
    short (*AR)[264] = (short(*)[264])(smem + 50688);
    float (*Zf)[260] = (float(*)[260])(smem + 67584);
    float (*SS)[32][68] = (float(*)[32][68])(smem + 100864);
    short (*PB)[32][72] = (short(*)[32][72])(smem + 118272);
    int* gp = (int*)(smem + 127488);

    if ((int)blockIdx.x >= *a.nchunks) return;
    int4 cd = a.chunks[blockIdx.x];
    int wl = cd.x, qstart = cd.y, qcnt = cd.z;
    int t = threadIdx.x;
    if (t < 32) gp[t] = (t < qcnt) ? a.perm[qstart + t] : a.perm[qstart];
    __syncthreads();

    int wv = t >> 6, lane = t & 63, quad = lane >> 4, l16 = lane & 15;
    int mt = wv & 1, g = wv >> 1;
    int laneRow = (mt << 4) + l16;
    int colbase = g << 7;
    int r8 = t >> 3, cq = (t & 7) << 5;  // LN mapping: 8 lanes/row, 32 cols each

#pragma unroll
    for (int l = 0; l < 2; ++l) {
        // ---------------- stage1: XH = LN(x)  (l=1: LN->ln_post0 affine->LN)
        {
            float4 v[8];
            if (l == 0) {
                const float* xp = a.xcur + (size_t)gp[r8] * 256 + cq;
#pragma unroll
                for (int gg = 0; gg < 8; ++gg) v[gg] = *(const float4*)(xp + (gg << 2));
            } else {
#pragma unroll
                for (int gg = 0; gg < 8; ++gg)
                    v[gg] = *(const float4*)&Zf[r8][cq + (gg << 2)];
            }
            float s = 0.f, ss = 0.f;
#pragma unroll
            for (int gg = 0; gg < 8; ++gg) {
                s += v[gg].x + v[gg].y + v[gg].z + v[gg].w;
                ss += v[gg].x * v[gg].x + v[gg].y * v[gg].y + v[gg].z * v[gg].z +
                      v[gg].w * v[gg].w;
            }
#pragma unroll
            for (int o = 1; o < 8; o <<= 1) {
                s += __shfl_xor(s, o, 64);
                ss += __shfl_xor(ss, o, 64);
            }
            float mu = s * (1.f / 256.f);
            float rs = rsqrtf(ss * (1.f / 256.f) - mu * mu + 1e-5f);
#pragma unroll
            for (int gg = 0; gg < 8; ++gg) {
                v[gg].x = (v[gg].x - mu) * rs;
                v[gg].y = (v[gg].y - mu) * rs;
                v[gg].z = (v[gg].z - mu) * rs;
                v[gg].w = (v[gg].w - mu) * rs;
            }
            if (l == 1) {
                float s2 = 0.f, ss2 = 0.f;
#pragma unroll
                for (int gg = 0; gg < 8; ++gg) {
                    float4 w4 = *(const float4*)&a.aw[cq + (gg << 2)];
                    float4 b4 = *(const float4*)&a.ab[cq + (gg << 2)];
                    v[gg].x = v[gg].x * w4.x + b4.x;
                    v[gg].y = v[gg].y * w4.y + b4.y;
                    v[gg].z = v[gg].z * w4.z + b4.z;
                    v[gg].w = v[gg].w * w4.w + b4.w;
                    s2 += v[gg].x + v[gg].y + v[gg].z + v[gg].w;
                    ss2 += v[gg].x * v[gg].x + v[gg].y * v[gg].y + v[gg].z * v[gg].z +
                           v[gg].w * v[gg].w;
                }
#pragma unroll
                for (int o = 1; o < 8; o <<= 1) {
                    s2 += __shfl_xor(s2, o, 64);
                    ss2 += __shfl_xor(ss2, o, 64);
                }
                float mu2 = s2 * (1.f / 256.f);
                float rs2 = rsqrtf(ss2 * (1.f / 256.f) - mu2 * mu2 + 1e-5f);
#pragma unroll
                for (int gg = 0; gg < 8; ++gg) {
                    v[gg].x = (v[gg].x - mu2) * rs2;
                    v[gg].y = (v[gg].y - mu2) * rs2;
                    v[gg].z = (v[gg].z - mu2) * rs2;
                    v[gg].w = (v[gg].w - mu2) * rs2;
                }
            }
#pragma unroll
            for (int gg = 0; gg < 8; ++gg) {
                short4v o;
                o[0] = (short)f2bf(v[gg].x);
                o[1] = (short)f2bf(v[gg].y);
                o[2] = (short)f2bf(v[gg].z);
                o[3] = (short)f2bf(v[gg].w);
                *(short4v*)&XH[r8][cq + (gg << 2)] = o;
            }
        }
        __syncthreads();

        // ---------------- Q: QR = XH @ Wq'^T + qb  (no barriers inside)
        {
            floatx4 acc[8];
#pragma unroll
            for (int i = 0; i < 8; ++i) acc[i] = (floatx4){0.f, 0.f, 0.f, 0.f};
            mgemm8((const short*)XH, 264, a.Wq[l], 256, 0, laneRow, colbase,
                   quad, l16, acc);
            const float* qb = a.qb[l];
#pragma unroll
            for (int i = 0; i < 8; ++i) {
                int col = colbase + (i << 4) + l16;
                float bv = qb[col];
#pragma unroll
                for (int r = 0; r < 4; ++r)
                    QR[(mt << 4) + (quad << 2) + r][col] = (short)f2bf(acc[i][r] + bv);
            }
        }
        __syncthreads();

        // ---------------- attention: 4 iterations x 2 concurrent heads
        {
            const unsigned short* Ktb = a.Ktb[l];
            const unsigned short* Vtb = a.Vtb[l];
            int p = g;         // head-pair slot for this wave
            int mtA = mt;
            // scores for head pair slot p, head index hd
            auto scores = [&](int hd) {
                short8 qa =
                    *(const short8*)&QR[(mtA << 4) + l16][(hd << 5) + (quad << 3)];
                const unsigned short* kbase =
                    Ktb + (size_t)(wl << 5) * 256 + (hd << 5) + (quad << 3);
                floatx4 c[4];
#pragma unroll
                for (int ct = 0; ct < 4; ++ct) {
                    short8 kb =
                        *(const short8*)(kbase + (size_t)((ct << 4) + l16) * 256);
                    floatx4 z = {0.f, 0.f, 0.f, 0.f};
                    c[ct] = __builtin_amdgcn_mfma_f32_16x16x32_bf16(qa, kb, z, 0, 0, 0);
                }
#pragma unroll
                for (int ct = 0; ct < 4; ++ct)
#pragma unroll
                    for (int r = 0; r < 4; ++r)
                        SS[p][(mtA << 4) + (quad << 2) + r][(ct << 4) + l16] =
                            c[ct][r];
            };
            auto pv = [&](int hd) {
                floatx4 o0 = {0.f, 0.f, 0.f, 0.f}, o1 = {0.f, 0.f, 0.f, 0.f};
                const unsigned short* vb = Vtb +
                    (size_t)((hd << 5) + l16) * M_DIM + (wl << 5) + (quad << 3);
#pragma unroll
                for (int ks = 0; ks < 2; ++ks) {
                    short8 pa = *(const short8*)&PB[p][(mtA << 4) + l16]
                                                  [(ks << 5) + (quad << 3)];
                    short8 v0 = *(const short8*)(vb + (ks << 5));
                    short8 v1 =
                        *(const short8*)(vb + (size_t)16 * M_DIM + (ks << 5));
                    o0 = __builtin_amdgcn_mfma_f32_16x16x32_bf16(pa, v0, o0, 0, 0, 0);
                    o1 = __builtin_amdgcn_mfma_f32_16x16x32_bf16(pa, v1, o1, 0, 0, 0);
                }
#pragma unroll
                for (int r = 0; r < 4; ++r) {
                    int row = (mtA << 4) + (quad << 2) + r;
                    AR[row][(hd << 5) + l16] = (short)f2bf(o0[r]);
                    AR[row][(hd << 5) + 16 + l16] = (short)f2bf(o1[r]);
                }
            };
            // softmax: independent thread mapping (2 heads x 32 rows x 64 cols)
            auto softmax = [&]() {
                int p2 = t >> 7;
                int row2 = (t >> 2) & 31;
                int sg2 = t & 3;
                float e[16];
                float s = 0.f;
#pragma unroll
                for (int c = 0; c < 16; ++c) {
                    e[c] = __expf(SS[p2][row2][(sg2 << 4) + c] * ATT_SCALE);
                    s += e[c];
                }
                s += __shfl_xor(s, 1, 64);
                s += __shfl_xor(s, 2, 64);
                float ri = 1.f / s;
                short8 o0, o1;
#pragma unroll
                for (int c = 0; c < 8; ++c) o0[c] = (short)f2bf(e[c] * ri);
#pragma unroll
                for (int c = 0; c < 8; ++c) o1[c] = (short)f2bf(e[c + 8] * ri);
                *(short8*)&PB[p2][row2][(sg2 << 4)] = o0;
                *(short8*)&PB[p2][row2][(sg2 << 4) + 8] = o1;
            };

            scores(p);
            __syncthreads();
            softmax();
            __syncthreads();
#pragma unroll 1
            for (int it = 0; it < 4; ++it) {
                pv((it << 1) + p);
                if (it < 3) scores(((it + 1) << 1) + p);
                __syncthreads();
                if (it < 3) {
                    softmax();
                    __syncthreads();
                }
            }
        }
        // (last attn barrier already issued) AR complete

        // ---------------- proj: Zf = AR @ Wp'^T + bproj  (fp32)
        {
            floatx4 acc[8];
#pragma unroll
            for (int i = 0; i < 8; ++i) acc[i] = (floatx4){0.f, 0.f, 0.f, 0.f};
            mgemm8((const short*)AR, 264, a.Wp[l], 256, 0, laneRow, colbase,
                   quad, l16, acc);
            const float* bpj = a.bpj[l];
#pragma unroll
            for (int i = 0; i < 8; ++i) {
                int col = colbase + (i << 4) + l16;
                float bv = bpj[col];
#pragma unroll
                for (int r = 0; r < 4; ++r)
                    Zf[(mt << 4) + (quad << 2) + r][col] = acc[i][r] + bv;
            }
        }
        __syncthreads();

        // ---------------- LNz: ZH = bf16(LN(Z)); Zf <- LN(Z)*pw + pb (residual)
        {
            const float* pw = a.pw[l];
            const float* pb = a.pb[l];
            float4 v[8];
#pragma unroll
            for (int gg = 0; gg < 8; ++gg)
                v[gg] = *(const float4*)&Zf[r8][cq + (gg << 2)];
            float s = 0.f, ss = 0.f;
#pragma unroll
            for (int gg = 0; gg < 8; ++gg) {
                s += v[gg].x + v[gg].y + v[gg].z + v[gg].w;
                ss += v[gg].x * v[gg].x + v[gg].y * v[gg].y + v[gg].z * v[gg].z +
                      v[gg].w * v[gg].w;
            }
#pragma unroll
            for (int o = 1; o < 8; o <<= 1) {
                s += __shfl_xor(s, o, 64);
                ss += __shfl_xor(ss, o, 64);
            }
            float mu = s * (1.f / 256.f);
            float rs = rsqrtf(ss * (1.f / 256.f) - mu * mu + 1e-5f);
#pragma unroll
            for (int gg = 0; gg < 8; ++gg) {
                float4 z;
                z.x = (v[gg].x - mu) * rs;
                z.y = (v[gg].y - mu) * rs;
                z.z = (v[gg].z - mu) * rs;
                z.w = (v[gg].w - mu) * rs;
                short4v o;
                o[0] = (short)f2bf(z.x);
                o[1] = (short)f2bf(z.y);
                o[2] = (short)f2bf(z.z);
                o[3] = (short)f2bf(z.w);
                *(short4v*)&ZH[r8][cq + (gg << 2)] = o;
                float4 w4 = *(const float4*)&pw[cq + (gg << 2)];
                float4 b4 = *(const float4*)&pb[cq + (gg << 2)];
                float4 za;
                za.x = z.x * w4.x + b4.x;
                za.y = z.y * w4.y + b4.y;
                za.z = z.z * w4.z + b4.z;
                za.w = z.w * w4.w + b4.w;
                *(float4*)&Zf[r8][cq + (gg << 2)] = za;
            }
        }
        __syncthreads();

        // ---------------- m1 half0 -> HH0(=XH region)
        short (*HH0)[264] = XH;
        short (*HH1)[264] = QR;
        const float* m1b = a.m1b[l];
        {
            floatx4 acc[8];
#pragma unroll
            for (int i = 0; i < 8; ++i) acc[i] = (floatx4){0.f, 0.f, 0.f, 0.f};
            mgemm8((const short*)ZH, 264, a.Wm1[l], 256, 0, laneRow, colbase,
                   quad, l16, acc);
#pragma unroll
            for (int i = 0; i < 8; ++i) {
                int col = colbase + (i << 4) + l16;
                float bv = m1b[col];
#pragma unroll
                for (int r = 0; r < 4; ++r)
                    HH0[(mt << 4) + (quad << 2) + r][col] =
                        (short)f2bf(gelu_exact(acc[i][r] + bv));
            }
        }
        __syncthreads();

        floatx4 macc[8];
#pragma unroll
        for (int i = 0; i < 8; ++i) macc[i] = (floatx4){0.f, 0.f, 0.f, 0.f};

        // ---------------- m1 half1 -> HH1(=QR region); m2 accum from HH0
        {
            floatx4 acc[8];
#pragma unroll
            for (int i = 0; i < 8; ++i) acc[i] = (floatx4){0.f, 0.f, 0.f, 0.f};
            mgemm8((const short*)ZH, 264, a.Wm1[l] + (size_t)256 * 256, 256, 0,
                   laneRow, colbase, quad, l16, acc);
            // m2 partial: K-range [0,256) from HH0
            mgemm8((const short*)HH0, 264, a.Wm2[l], 512, 0, laneRow, colbase,
                   quad, l16, macc);
#pragma unroll
            for (int i = 0; i < 8; ++i) {
                int col = colbase + (i << 4) + l16;
                float bv = m1b[256 + col];
#pragma unroll
                for (int r = 0; r < 4; ++r)
                    HH1[(mt << 4) + (quad << 2) + r][col] =
                        (short)f2bf(gelu_exact(acc[i][r] + bv));
            }
        }
        __syncthreads();

        // ---------------- m2 half1 from HH1; epilogue residual in-place
        {
            mgemm8((const short*)HH1, 264, a.Wm2[l], 512, 256, laneRow, colbase,
                   quad, l16, macc);
            const float* b2 = a.bm2v[l];
#pragma unroll
            for (int i = 0; i < 8; ++i) {
                int col = colbase + (i << 4) + l16;
                float bv = b2[col];
#pragma unroll
                for (int r = 0; r < 4; ++r) {
                    int row = (mt << 4) + (quad << 2) + r;
                    float v = macc[i][r] + bv + Zf[row][col];
                    if (l == 0) {
                        Zf[row][col] = v;
                    } else if (row < qcnt) {
                        a.xfinal[(size_t)gp[row] * 256 + col] = v;
                    }
                }
            }
        }
        __syncthreads();
    }
}

// ======================= final: LN_post + L2 norm + transpose ==============
__global__ __launch_bounds__(256) void out_kernel(const float* __restrict__ X,
                                                  const float* __restrict__ w,
                                                  const float* __restrict__ b,
                                                  float* __restrict__ out) {
    __shared__ float tile[64][65];
    int t = threadIdx.x;
    int mo = t >> 2, q = t & 3;
    int m0 = blockIdx.x << 6;
    const float* p = X + (size_t)(m0 + mo) * C_DIM + (q << 6);
    float4 v[16];
    float s = 0.f, ss = 0.f;
#pragma unroll
    for (int c = 0; c < 16; ++c) {
        v[c] = *(const float4*)(p + c * 4);
        s += v[c].x + v[c].y + v[c].z + v[c].w;
        ss += v[c].x * v[c].x + v[c].y * v[c].y + v[c].z * v[c].z + v[c].w * v[c].w;
    }
    s += __shfl_xor(s, 1, 64); s += __shfl_xor(s, 2, 64);
    ss += __shfl_xor(ss, 1, 64); ss += __shfl_xor(ss, 2, 64);
    float mu = s * (1.f / 256.f);
    float rs = rsqrtf(ss * (1.f / 256.f) - mu * mu + 1e-5f);
    float ss2 = 0.f;
#pragma unroll
    for (int c = 0; c < 16; ++c) {
        float4 w4 = *(const float4*)&w[(q << 6) + c * 4];
        float4 b4 = *(const float4*)&b[(q << 6) + c * 4];
        v[c].x = (v[c].x - mu) * rs * w4.x + b4.x;
        v[c].y = (v[c].y - mu) * rs * w4.y + b4.y;
        v[c].z = (v[c].z - mu) * rs * w4.z + b4.z;
        v[c].w = (v[c].w - mu) * rs * w4.w + b4.w;
        ss2 += v[c].x * v[c].x + v[c].y * v[c].y + v[c].z * v[c].z + v[c].w * v[c].w;
    }
    ss2 += __shfl_xor(ss2, 1, 64); ss2 += __shfl_xor(ss2, 2, 64);
    float sc = 1.f / fmaxf(sqrtf(ss2), 1e-12f);
    for (int cc = 0; cc < 4; ++cc) {
        if (q == cc) {
#pragma unroll
            for (int c = 0; c < 16; ++c) {
                tile[mo][c * 4 + 0] = v[c].x * sc;
                tile[mo][c * 4 + 1] = v[c].y * sc;
                tile[mo][c * 4 + 2] = v[c].z * sc;
                tile[mo][c * 4 + 3] = v[c].w * sc;
            }
        }
        __syncthreads();
        for (int it = 0; it < 16; ++it) {
            int idx = it * 256 + t;
            int co = idx >> 6, mr = idx & 63;
            out[(size_t)((cc << 6) + co) * M_DIM + m0 + mr] = tile[mr][co];
        }
        __syncthreads();
    }
}

// ---------------------------------------------------------------------------
extern "C" void kernel_launch(void* const* d_in, const int* in_sizes, int n_in,
                              void* d_out, int out_size, void* d_ws, size_t ws_size,
                              hipStream_t stream) {
    const float* grd2sat = (const float*)d_in[0];
    const float* grd_x   = (const float*)d_in[1];
    const float* u       = (const float*)d_in[2];
    const float* ln_q_w  = (const float*)d_in[3];
    const float* ln_q_b  = (const float*)d_in[4];
    const float* ln_k_w  = (const float*)d_in[5];
    const float* ln_k_b  = (const float*)d_in[6];
    const float* ln_v_w  = (const float*)d_in[7];
    const float* ln_v_b  = (const float*)d_in[8];
    const float* Wq      = (const float*)d_in[9];
    const float* Wk      = (const float*)d_in[10];
    const float* Wv      = (const float*)d_in[11];
    const float* Wproj   = (const float*)d_in[12];
    const float* bproj   = (const float*)d_in[13];
    const float* ln_pre_w = (const float*)d_in[14];
    const float* ln_pre_b = (const float*)d_in[15];
    const float* Wm1     = (const float*)d_in[16];
    const float* bm1     = (const float*)d_in[17];
    const float* Wm2     = (const float*)d_in[18];
    const float* bm2     = (const float*)d_in[19];
    const float* ln_post_w = (const float*)d_in[20];
    const float* ln_post_b = (const float*)d_in[21];

    float* ws   = (float*)d_ws;
    float* yhat = ws;                        // 4 MB
    float* xcur = ws + 1048576;              // 4 MB
    float* zq   = ws + 2097152;              // 4 MB (xfinal)
    unsigned short* Ktab0 = (unsigned short*)(ws + 6291456); // 2 MB
    unsigned short* Vt0   = (unsigned short*)(ws + 6815744); // 2 MB
    unsigned short* Ktab1 = (unsigned short*)(ws + 7340032); // 2 MB
    unsigned short* Vt1   = (unsigned short*)(ws + 7864320); // 2 MB
    unsigned short* Bt    = (unsigned short*)(ws + 8388608); // 2 MB (both blocks)
    float* biasbuf = ws + 8912896;           // 2560 floats
    int*  perm    = (int*)(ws + 8915456);    // 4096 ints
    int4* chunks  = (int4*)(ws + 8919552);   // 512 int4
    int*  nchunks = (int*)(ws + 8921600);
    const size_t BS = 524288;
    const size_t OQ = 0, OKV = 65536, OP = 196608, OM1 = 262144, OM2 = 393216;

    dim3 b256(256);

    PrepArgs pa;
    pa.grd2sat = grd2sat; pa.xcur = xcur;
    pa.grd_x = grd_x;     pa.yhat = yhat;
    pa.u = u; pa.perm = perm; pa.chunks = chunks; pa.nchunks = nchunks;
    {
        int base = 0;
        for (int i = 0; i < 2; ++i) {
            int e = 6 * i;
            unsigned short* bt = Bt + i * BS;
            pa.win[e+0] = Wq + i * 65536;    pa.wout[e+0] = bt + OQ;
            pa.wlnw[e+0] = ln_q_w + i * 256; pa.wR[e+0] = 256; pa.wC[e+0] = 256;
            pa.win[e+1] = Wk + i * 65536;    pa.wout[e+1] = bt + OKV;
            pa.wlnw[e+1] = ln_k_w + i * 256; pa.wR[e+1] = 256; pa.wC[e+1] = 256;
            pa.win[e+2] = Wv + i * 65536;    pa.wout[e+2] = bt + OKV + 65536;
            pa.wlnw[e+2] = ln_v_w + i * 256; pa.wR[e+2] = 256; pa.wC[e+2] = 256;
            pa.win[e+3] = Wproj + i * 65536; pa.wout[e+3] = bt + OP;
            pa.wlnw[e+3] = nullptr;          pa.wR[e+3] = 256; pa.wC[e+3] = 256;
            pa.win[e+4] = Wm1 + i * 131072;  pa.wout[e+4] = bt + OM1;
            pa.wlnw[e+4] = ln_pre_w + i * 256; pa.wR[e+4] = 256; pa.wC[e+4] = 512;
            pa.win[e+5] = Wm2 + i * 131072;  pa.wout[e+5] = bt + OM2;
            pa.wlnw[e+5] = nullptr;          pa.wR[e+5] = 512; pa.wC[e+5] = 256;
        }
        for (int e = 0; e < 12; ++e) {
            pa.wbase[e] = base;
            base += (pa.wR[e] >> 5) * (pa.wC[e] >> 5);
        }
        pa.wbase[12] = base;  // 1024
        for (int i = 0; i < 2; ++i) {
            int jb = 5 * i;
            float* bb = biasbuf + i * 1280;
            pa.fW[jb+0] = Wq + i * 65536; pa.flnb[jb+0] = ln_q_b + i * 256;
            pa.fbase[jb+0] = nullptr; pa.fout[jb+0] = bb;
            pa.fN[jb+0] = 256; pa.fwcol[jb+0] = 0; pa.focol[jb+0] = 0;
            pa.fW[jb+1] = Wk + i * 65536; pa.flnb[jb+1] = ln_k_b + i * 256;
            pa.fbase[jb+1] = nullptr; pa.fout[jb+1] = bb + 256;
            pa.fN[jb+1] = 256; pa.fwcol[jb+1] = 0; pa.focol[jb+1] = 0;
            pa.fW[jb+2] = Wv + i * 65536; pa.flnb[jb+2] = ln_v_b + i * 256;
            pa.fbase[jb+2] = nullptr; pa.fout[jb+2] = bb + 256;
            pa.fN[jb+2] = 256; pa.fwcol[jb+2] = 0; pa.focol[jb+2] = 256;
            pa.fW[jb+3] = Wm1 + i * 131072; pa.flnb[jb+3] = ln_pre_b + i * 256;
            pa.fbase[jb+3] = bm1 + i * 512; pa.fout[jb+3] = bb + 768;
            pa.fN[jb+3] = 512; pa.fwcol[jb+3] = 0; pa.focol[jb+3] = 0;
            pa.fW[jb+4] = Wm1 + i * 131072; pa.flnb[jb+4] = ln_pre_b + i * 256;
            pa.fbase[jb+4] = bm1 + i * 512; pa.fout[jb+4] = bb + 768;
            pa.fN[jb+4] = 512; pa.fwcol[jb+4] = 256; pa.focol[jb+4] = 256;
        }
    }
    prep_kernel<<<1419, b256, 0, stream>>>(pa);

    // ---- K/V tables for both transformer blocks
    GJ jkv0 = {};
    jkv0.A = yhat; jkv0.Bt = Bt + OKV; jkv0.bias = biasbuf + 256;
    jkv0.out = Ktab0; jkv0.out2 = Vt0; jkv0.K = 256; jkv0.N = 512;
    GJ jkv1 = {};
    jkv1.A = yhat; jkv1.Bt = Bt + BS + OKV; jkv1.bias = biasbuf + 1280 + 256;
    jkv1.out = Ktab1; jkv1.out2 = Vt1; jkv1.K = 256; jkv1.N = 512;
    kv_kernel<<<dim3(128, 16), b256, 0, stream>>>(jkv0, jkv1);

    // ---- mega chunk kernel v2
    MegaArgs ma;
    ma.xcur = xcur; ma.perm = perm; ma.chunks = chunks; ma.nchunks = nchunks;
    ma.xfinal = zq;
    for (int i = 0; i < 2; ++i) {
        const unsigned short* bt = Bt + i * BS;
        ma.Wq[i] = bt + OQ; ma.Wp[i] = bt + OP;
        ma.Wm1[i] = bt + OM1; ma.Wm2[i] = bt + OM2;
        ma.Ktb[i] = i ? Ktab1 : Ktab0; ma.Vtb[i] = i ? Vt1 : Vt0;
        ma.qb[i] = biasbuf + i * 1280;
        ma.m1b[i] = biasbuf + i * 1280 + 768;
        ma.bpj[i] = bproj + i * 256;
        ma.bm2v[i] = bm2 + i * 256;
        ma.pw[i] = ln_pre_w + i * 256;
        ma.pb[i] = ln_pre_b + i * 256;
    }
    ma.aw = ln_post_w; ma.ab = ln_post_b;  // block 0 ln_post for layer-1 LN2
    mega_kernel<<<288, b256, 0, stream>>>(ma);

    out_kernel<<<64, b256, 0, stream>>>(zq, ln_post_w + 256, ln_post_b + 256,
                                        (float*)d_out);
}

// Round 3
// 253.873 us; speedup vs baseline: 1.1341x; 1.1341x over previous
//
#include <hip/hip_runtime.h>
#include <math.h>

// ---------------------------------------------------------------------------
// CrossViewAttention — R7: mega v3 — 512 threads (2 waves/SIMD), one-head-
// per-wave attention with in-wave softmax, 7 barriers/layer, prep fbias fix.
// B=1, C=256, M=4096, W=128, H=32, BLOCKS=2, HEADS=8, DH=32
// ---------------------------------------------------------------------------

#define C_DIM 256
#define M_DIM 4096
#define W_DIM 128
#define H_DIM 32
#define ATT_SCALE 0.17677669529663687f  // 1/sqrt(32)

typedef __attribute__((ext_vector_type(8))) short short8;
typedef __attribute__((ext_vector_type(4))) short short4v;
typedef __attribute__((ext_vector_type(4))) float floatx4;

__device__ __forceinline__ unsigned short f2bf(float f) {
    unsigned u = __float_as_uint(f);
    unsigned r = (u + 0x7fffu + ((u >> 16) & 1u)) >> 16;
    return (unsigned short)r;
}
__device__ __forceinline__ float gelu_exact(float x) {
    return 0.5f * x * (1.0f + erff(x * 0.70710678118654752f));
}

// ======================= mega prep kernel ==================================
// roles by blockIdx.x:
//   [0,256)     transpose grd2sat (C,M) -> xcur (M,C)
//   [256,384)   yhat: LN over C of grd_x columns
//   [384,1408)  weight transpose+scale+convert
//   [1408,1448) folded biases: 10 jobs x 4 col-parts, k split 4-way in-block
//   1448        bucket sort of queries by wl=floor(u)
struct PrepArgs {
    const float* grd2sat; float* xcur;
    const float* grd_x;   float* yhat;
    const float* u; int* perm; int4* chunks; int* nchunks;
    const float* win[12]; unsigned short* wout[12]; const float* wlnw[12];
    int wR[12], wC[12], wbase[13];
    const float* fW[10]; const float* flnb[10]; const float* fbase[10];
    float* fout[10];
    int fN[10], fwcol[10], focol[10];
};

__global__ __launch_bounds__(256) void prep_kernel(PrepArgs a) {
    __shared__ float smemf[9024];
    int b = blockIdx.x, t = threadIdx.x;
    if (b < 256) {
        float (*tile)[65] = (float(*)[65])smemf;
        int m0 = (b & 63) << 6, c0 = (b >> 6) << 6;
        for (int it = 0; it < 16; ++it) {
            int idx = it * 256 + t;
            int co = idx >> 6, mo = idx & 63;
            tile[co][mo] = a.grd2sat[(size_t)(c0 + co) * M_DIM + m0 + mo];
        }
        __syncthreads();
        for (int it = 0; it < 16; ++it) {
            int idx = it * 256 + t;
            int mo = idx >> 6, co = idx & 63;
            a.xcur[(size_t)(m0 + mo) * C_DIM + c0 + co] = tile[co][mo];
        }
    } else if (b < 384) {
        int idx = b - 256;
        int h = idx & 31, w0 = (idx >> 5) << 5;
        float (*tile)[33] = (float(*)[33])smemf;
        float (*ps)[32] = (float(*)[32])(smemf + 8448);
        float (*pss)[32] = (float(*)[32])(smemf + 8704);
        float* mu_s = smemf + 8960;
        float* rs_s = smemf + 8992;
        int wo = t & 31, cb = t >> 5;
        for (int it = 0; it < 32; ++it) {
            int c = it * 8 + cb;
            tile[c][wo] = a.grd_x[(size_t)c * (H_DIM * W_DIM) + h * W_DIM + w0 + wo];
        }
        __syncthreads();
        {
            int w = t & 31, part = t >> 5;
            float s = 0.f, ss = 0.f;
            for (int c = part * 32; c < part * 32 + 32; ++c) {
                float x = tile[c][w];
                s += x; ss += x * x;
            }
            ps[part][w] = s; pss[part][w] = ss;
        }
        __syncthreads();
        if (t < 32) {
            float s = 0.f, ss = 0.f;
            for (int p = 0; p < 8; ++p) { s += ps[p][t]; ss += pss[p][t]; }
            float mu = s * (1.f / 256.f);
            float var = ss * (1.f / 256.f) - mu * mu;
            mu_s[t] = mu;
            rs_s[t] = rsqrtf(var + 1e-5f);
        }
        __syncthreads();
        for (int jj = 0; jj < 32; ++jj) {
            float mu = mu_s[jj], rs = rs_s[jj];
            a.yhat[((size_t)(w0 + jj) * H_DIM + h) * C_DIM + t] =
                (tile[t][jj] - mu) * rs;
        }
    } else if (b < 1408) {
        int wI = b - 384;
        int e = 0;
        while (wI >= a.wbase[e + 1]) ++e;
        int tl = wI - a.wbase[e];
        int tilesC = a.wC[e] >> 5;
        int tr = tl / tilesC, tc = tl - tr * tilesC;
        int r0 = tr << 5, c0 = tc << 5;
        const float* in = a.win[e];
        unsigned short* out = a.wout[e];
        const float* lnw = a.wlnw[e];
        int R = a.wR[e], Cc = a.wC[e];
        float (*tile)[33] = (float(*)[33])smemf;
        int rl = t >> 3, cq = (t & 7) << 2;
        float4 v = *(const float4*)&in[(size_t)(r0 + rl) * Cc + c0 + cq];
        if (lnw) {
            float s = lnw[r0 + rl];
            v.x *= s; v.y *= s; v.z *= s; v.w *= s;
        }
        tile[rl][cq + 0] = v.x;
        tile[rl][cq + 1] = v.y;
        tile[rl][cq + 2] = v.z;
        tile[rl][cq + 3] = v.w;
        __syncthreads();
        int cl = t >> 3, rq = (t & 7) << 2;
        ushort4 o;
        o.x = f2bf(tile[rq + 0][cl]);
        o.y = f2bf(tile[rq + 1][cl]);
        o.z = f2bf(tile[rq + 2][cl]);
        o.w = f2bf(tile[rq + 3][cl]);
        *(ushort4*)&out[(size_t)(c0 + cl) * R + r0 + rq] = o;
    } else if (b < 1448) {
        int idx = b - 1408;            // 0..39
        int jj = idx >> 2, part = idx & 3;
        int N = a.fN[jj];
        int c = t & 63, kp = t >> 6;   // 4 k-parts of 64
        int wcol = a.fwcol[jj] + (part << 6) + c;
        const float* W = a.fW[jj];
        const float* lb = a.flnb[jj];
        float s = 0.f;
        for (int k = kp * 64; k < kp * 64 + 64; ++k)
            s += lb[k] * W[(size_t)k * N + wcol];
        smemf[(kp << 6) + c] = s;
        __syncthreads();
        if (t < 64) {
            float tot = smemf[t] + smemf[64 + t] + smemf[128 + t] + smemf[192 + t];
            int ocol = a.focol[jj] + (part << 6) + t;
            if (a.fbase[jj]) tot += a.fbase[jj][a.fwcol[jj] + (part << 6) + t];
            a.fout[jj][ocol] = tot;
        }
    } else {
        int* hist = (int*)smemf;
        int* cur = (int*)smemf + 128;
        unsigned short* wlb = (unsigned short*)((int*)smemf + 256);
        if (t < 128) hist[t] = 0;
        __syncthreads();
        for (int it = 0; it < 16; ++it) {
            int m = it * 256 + t;
            int wl = (int)floorf(a.u[m]);
            wl = max(0, min(wl, 126));
            wlb[m] = (unsigned short)wl;
            atomicAdd(&hist[wl], 1);
        }
        __syncthreads();
        if (t == 0) {
            int run = 0, nc = 0;
            for (int bkt = 0; bkt < 127; ++bkt) {
                int c = hist[bkt];
                cur[bkt] = run;
                int q0 = run;
                while (c > 0) {
                    int take = min(c, 32);
                    a.chunks[nc] = make_int4(bkt, q0, take, 0);
                    ++nc; q0 += take; c -= take;
                }
                run += hist[bkt];
            }
            *a.nchunks = nc;
        }
        __syncthreads();
        for (int it = 0; it < 16; ++it) {
            int m = it * 256 + t;
            int wl = wlb[m];
            int pos = atomicAdd(&cur[wl], 1);
            a.perm[pos] = m;
        }
    }
}

// ======================= KV GEMM (unchanged structure) =====================
struct GJ {
    const void* A; const unsigned short* Bt;
    const float* bias;
    void* out; unsigned short* out2;
    int K, N;
};

__device__ __forceinline__ void gemm_core_kv(const GJ& j, short (*As)[264],
                                             short (*Bs)[264], int bm, int by) {
    int t = threadIdx.x;
    int bn = by << 6;
    int wv = t >> 6, lane = t & 63;
    int mt = wv & 1, nt0 = (wv >> 1) << 1;
    int quad = lane >> 4, l16 = lane & 15;
    floatx4 acc0 = {0.f, 0.f, 0.f, 0.f};
    floatx4 acc1 = {0.f, 0.f, 0.f, 0.f};
    {
        int ar = t >> 3, cq = (t & 7) << 2;
        const float* ap = (const float*)j.A + (size_t)(bm + ar) * 256 + cq;
        float4 v[8];
#pragma unroll
        for (int g = 0; g < 8; ++g) v[g] = *(const float4*)(ap + g * 32);
#pragma unroll
        for (int g = 0; g < 8; ++g) {
            short4v o;
            o[0] = (short)f2bf(v[g].x);
            o[1] = (short)f2bf(v[g].y);
            o[2] = (short)f2bf(v[g].z);
            o[3] = (short)f2bf(v[g].w);
            *(short4v*)&As[ar][cq + g * 32] = o;
        }
    }
    {
        int br = t >> 2, cq2 = (t & 3) << 3;
        const unsigned short* bp = j.Bt + (size_t)(bn + br) * 256 + cq2;
#pragma unroll
        for (int g = 0; g < 8; ++g)
            *(short8*)&Bs[br][cq2 + g * 32] = *(const short8*)(bp + g * 32);
    }
    __syncthreads();
#pragma unroll
    for (int k0 = 0; k0 < 8; ++k0) {
        short8 aa = *(const short8*)&As[(mt << 4) + l16][(k0 << 5) + (quad << 3)];
        short8 b0 = *(const short8*)&Bs[(nt0 << 4) + l16][(k0 << 5) + (quad << 3)];
        short8 b1 =
            *(const short8*)&Bs[((nt0 + 1) << 4) + l16][(k0 << 5) + (quad << 3)];
        acc0 = __builtin_amdgcn_mfma_f32_16x16x32_bf16(aa, b0, acc0, 0, 0, 0);
        acc1 = __builtin_amdgcn_mfma_f32_16x16x32_bf16(aa, b1, acc1, 0, 0, 0);
    }
#pragma unroll
    for (int jj = 0; jj < 2; ++jj) {
        const floatx4 accv = jj ? acc1 : acc0;
        int col = bn + ((nt0 + jj) << 4) + l16;
        float bv = j.bias[col];
#pragma unroll
        for (int r = 0; r < 4; ++r) {
            int row = bm + (mt << 4) + (quad << 2) + r;
            float v = accv[r] + bv;
            if (col < 256)
                ((unsigned short*)j.out)[(size_t)row * 256 + col] = f2bf(v);
            else
                j.out2[(size_t)(col - 256) * M_DIM + row] = f2bf(v);
        }
    }
}

__global__ __launch_bounds__(256) void kv_kernel(GJ j0, GJ j1) {
    __shared__ short As[32][264];
    __shared__ short Bs[64][264];
    int bm = blockIdx.x << 5;
    if ((int)blockIdx.y < 8)
        gemm_core_kv(j0, As, Bs, bm, blockIdx.y);
    else
        gemm_core_kv(j1, As, Bs, bm, blockIdx.y - 8);
}

// ======================= mega chunk kernel v3 (512 threads) ================
struct MegaArgs {
    const float* xcur;
    const int* perm; const int4* chunks; const int* nchunks;
    float* xfinal;
    const unsigned short* Wq[2]; const unsigned short* Wp[2];
    const unsigned short* Wm1[2]; const unsigned short* Wm2[2];
    const unsigned short* Ktb[2]; const unsigned short* Vtb[2];
    const float* qb[2]; const float* m1b[2];
    const float* bpj[2]; const float* bm2v[2];
    const float* pw[2]; const float* pb[2];
    const float* aw; const float* ab;  // ln_post[0] for layer-1 LN2
};

// 4-tile merged GEMM: 32 rows (LDS bf16 A, pitch lda) x 64 cols per wave.
__device__ __forceinline__ void mgemm4(const short* As, int lda,
                                       const unsigned short* Bt, int Kstride,
                                       int kcB, int laneRow, int colbase,
                                       int quad, int l16, floatx4 acc[4]) {
    const short* ap = As + (size_t)laneRow * lda + (quad << 3);
    const unsigned short* bp =
        Bt + (size_t)(colbase + l16) * Kstride + kcB + (quad << 3);
#pragma unroll
    for (int k0 = 0; k0 < 8; ++k0) {
        short8 aa = *(const short8*)(ap + (k0 << 5));
#pragma unroll
        for (int i = 0; i < 4; ++i) {
            short8 bb =
                *(const short8*)(bp + (size_t)(i << 4) * Kstride + (k0 << 5));
            acc[i] = __builtin_amdgcn_mfma_f32_16x16x32_bf16(aa, bb, acc[i], 0, 0, 0);
        }
    }
}

// 8-tile variant (m1, 128 cols per wave).
__device__ __forceinline__ void mgemm8(const short* As, int lda,
                                       const unsigned short* Bt, int Kstride,
                                       int laneRow, int colbase,
                                       int quad, int l16, floatx4 acc[8]) {
    const short* ap = As + (size_t)laneRow * lda + (quad << 3);
    const unsigned short* bp =
        Bt + (size_t)(colbase + l16) * Kstride + (quad << 3);
#pragma unroll
    for (int k0 = 0; k0 < 8; ++k0) {
        short8 aa = *(const short8*)(ap + (k0 << 5));
#pragma unroll
        for (int i = 0; i < 8; ++i) {
            short8 bb =
                *(const short8*)(bp + (size_t)(i << 4) * Kstride + (k0 << 5));
            acc[i] = __builtin_amdgcn_mfma_f32_16x16x32_bf16(aa, bb, acc[i], 0, 0, 0);
        }
    }
}

// LDS layout (bytes):
//  [0,      16896)  XH short[32][264]  (stage1->Q) / HH0 (m1 cols 0-255)
//  [16896,  33792)  QR short[32][264]  (Q->attn)   / HH1 (m1 cols 256-511)
//  [33792,  50688)  ZH short[32][264]  (LNz->m1)
//  [50688,  67584)  AR short[32][264]  (attn->proj)
//  [67584, 100864)  Zf float[32][260]  (proj z; residual; x' in-place)
//  [100864,137728)  PB short[8][32][72] (per-wave softmax P slot)
//  [137728,137856)  gperm int[32]
__global__ __launch_bounds__(512, 2) void mega_kernel(MegaArgs a) {
    __shared__ __align__(16) char smem[137856];
    short (*XH)[264] = (short(*)[264])(smem);
    short (*QR)[264] = (short(*)[264])(smem + 16896);
    short (*ZH)[264] = (short(*)[264])(smem + 33792);
    short (*AR)[264] = (short(*)[264])(smem + 50688);
    float (*Zf)[260] = (float(*)[260])(smem + 67584);
    short (*PB)[32][72] = (short(*)[32][72])(smem + 100864);
    int* gp = (int*)(smem + 137728);

    if ((int)blockIdx.x >= *a.nchunks) return;
    int4 cd = a.chunks[blockIdx.x];
    int wl = cd.x, qstart = cd.y, qcnt = cd.z;
    int t = threadIdx.x;
    if (t < 32) gp[t] = (t < qcnt) ? a.perm[qstart + t] : a.perm[qstart];
    __syncthreads();

    int wv = t >> 6, lane = t & 63, quad = lane >> 4, l16 = lane & 15;
    int mt = wv & 1, g = wv >> 1;
    int laneRow = (mt << 4) + l16;
    int colbase = g << 6;
    int r16 = t >> 4, c0 = (t & 15) << 4;  // LN mapping: 16 lanes/row, 16 cols

#pragma unroll 1
    for (int l = 0; l < 2; ++l) {
        // ---------------- stage1: XH = LN(x) (l=1: LN->ln_post0 affine->LN)
        {
            float4 v[4];
            if (l == 0) {
                const float* xp = a.xcur + (size_t)gp[r16] * 256 + c0;
#pragma unroll
                for (int g4 = 0; g4 < 4; ++g4)
                    v[g4] = *(const float4*)(xp + (g4 << 2));
            } else {
#pragma unroll
                for (int g4 = 0; g4 < 4; ++g4)
                    v[g4] = *(const float4*)&Zf[r16][c0 + (g4 << 2)];
            }
            float s = 0.f, ss = 0.f;
#pragma unroll
            for (int g4 = 0; g4 < 4; ++g4) {
                s += v[g4].x + v[g4].y + v[g4].z + v[g4].w;
                ss += v[g4].x * v[g4].x + v[g4].y * v[g4].y + v[g4].z * v[g4].z +
                      v[g4].w * v[g4].w;
            }
#pragma unroll
            for (int o = 1; o < 16; o <<= 1) {
                s += __shfl_xor(s, o, 64);
                ss += __shfl_xor(ss, o, 64);
            }
            float mu = s * (1.f / 256.f);
            float rs = rsqrtf(ss * (1.f / 256.f) - mu * mu + 1e-5f);
#pragma unroll
            for (int g4 = 0; g4 < 4; ++g4) {
                v[g4].x = (v[g4].x - mu) * rs;
                v[g4].y = (v[g4].y - mu) * rs;
                v[g4].z = (v[g4].z - mu) * rs;
                v[g4].w = (v[g4].w - mu) * rs;
            }
            if (l == 1) {
                float s2 = 0.f, ss2 = 0.f;
#pragma unroll
                for (int g4 = 0; g4 < 4; ++g4) {
                    float4 w4 = *(const float4*)&a.aw[c0 + (g4 << 2)];
                    float4 b4 = *(const float4*)&a.ab[c0 + (g4 << 2)];
                    v[g4].x = v[g4].x * w4.x + b4.x;
                    v[g4].y = v[g4].y * w4.y + b4.y;
                    v[g4].z = v[g4].z * w4.z + b4.z;
                    v[g4].w = v[g4].w * w4.w + b4.w;
                    s2 += v[g4].x + v[g4].y + v[g4].z + v[g4].w;
                    ss2 += v[g4].x * v[g4].x + v[g4].y * v[g4].y +
                           v[g4].z * v[g4].z + v[g4].w * v[g4].w;
                }
#pragma unroll
                for (int o = 1; o < 16; o <<= 1) {
                    s2 += __shfl_xor(s2, o, 64);
                    ss2 += __shfl_xor(ss2, o, 64);
                }
                float mu2 = s2 * (1.f / 256.f);
                float rs2 = rsqrtf(ss2 * (1.f / 256.f) - mu2 * mu2 + 1e-5f);
#pragma unroll
                for (int g4 = 0; g4 < 4; ++g4) {
                    v[g4].x = (v[g4].x - mu2) * rs2;
                    v[g4].y = (v[g4].y - mu2) * rs2;
                    v[g4].z = (v[g4].z - mu2) * rs2;
                    v[g4].w = (v[g4].w - mu2) * rs2;
                }
            }
#pragma unroll
            for (int g4 = 0; g4 < 4; ++g4) {
                short4v o;
                o[0] = (short)f2bf(v[g4].x);
                o[1] = (short)f2bf(v[g4].y);
                o[2] = (short)f2bf(v[g4].z);
                o[3] = (short)f2bf(v[g4].w);
                *(short4v*)&XH[r16][c0 + (g4 << 2)] = o;
            }
        }
        __syncthreads();

        // ---------------- Q: QR = XH @ Wq'^T + qb
        {
            floatx4 acc[4];
#pragma unroll
            for (int i = 0; i < 4; ++i) acc[i] = (floatx4){0.f, 0.f, 0.f, 0.f};
            mgemm4((const short*)XH, 264, a.Wq[l], 256, 0, laneRow, colbase,
                   quad, l16, acc);
            const float* qb = a.qb[l];
#pragma unroll
            for (int i = 0; i < 4; ++i) {
                int col = colbase + (i << 4) + l16;
                float bv = qb[col];
#pragma unroll
                for (int r = 0; r < 4; ++r)
                    QR[(mt << 4) + (quad << 2) + r][col] =
                        (short)f2bf(acc[i][r] + bv);
            }
        }
        __syncthreads();

        // ---------------- attention: one head per wave, in-wave softmax
        {
            int h = wv;
            const unsigned short* Kt = a.Ktb[l];
            const unsigned short* Vt = a.Vtb[l];
            short8 aq0 = *(const short8*)&QR[l16][(h << 5) + (quad << 3)];
            short8 aq1 = *(const short8*)&QR[16 + l16][(h << 5) + (quad << 3)];
            floatx4 c[2][4];
#pragma unroll
            for (int nt = 0; nt < 4; ++nt) {
                short8 kb = *(const short8*)(
                    Kt + (size_t)((wl << 5) + (nt << 4) + l16) * 256 +
                    (h << 5) + (quad << 3));
                floatx4 z = {0.f, 0.f, 0.f, 0.f};
                c[0][nt] = __builtin_amdgcn_mfma_f32_16x16x32_bf16(aq0, kb, z, 0, 0, 0);
                c[1][nt] = __builtin_amdgcn_mfma_f32_16x16x32_bf16(aq1, kb, z, 0, 0, 0);
            }
            // exp + row-sum (rows live in quad/r; cols in l16 x nt)
            floatx4 ri[2];
#pragma unroll
            for (int m = 0; m < 2; ++m) {
#pragma unroll
                for (int nt = 0; nt < 4; ++nt) {
                    floatx4 e;
#pragma unroll
                    for (int r = 0; r < 4; ++r)
                        e[r] = __expf(c[m][nt][r] * ATT_SCALE);
                    c[m][nt] = e;
                }
                floatx4 s4 = c[m][0] + c[m][1] + c[m][2] + c[m][3];
#pragma unroll
                for (int r = 0; r < 4; ++r) {
                    float s = s4[r];
                    s += __shfl_xor(s, 1, 64);
                    s += __shfl_xor(s, 2, 64);
                    s += __shfl_xor(s, 4, 64);
                    s += __shfl_xor(s, 8, 64);
                    ri[m][r] = 1.f / s;
                }
            }
            // write normalized P (bf16) to this wave's private slot
#pragma unroll
            for (int m = 0; m < 2; ++m)
#pragma unroll
                for (int nt = 0; nt < 4; ++nt)
#pragma unroll
                    for (int r = 0; r < 4; ++r)
                        PB[wv][(m << 4) + (quad << 2) + r][(nt << 4) + l16] =
                            (short)f2bf(c[m][nt][r] * ri[m][r]);
            __threadfence_block();  // order intra-wave LDS write->read
            // PV
            floatx4 o[2][2];
#pragma unroll
            for (int m = 0; m < 2; ++m)
#pragma unroll
                for (int dt = 0; dt < 2; ++dt)
                    o[m][dt] = (floatx4){0.f, 0.f, 0.f, 0.f};
#pragma unroll
            for (int ks = 0; ks < 2; ++ks) {
                short8 pa0 =
                    *(const short8*)&PB[wv][l16][(ks << 5) + (quad << 3)];
                short8 pa1 =
                    *(const short8*)&PB[wv][16 + l16][(ks << 5) + (quad << 3)];
#pragma unroll
                for (int dt = 0; dt < 2; ++dt) {
                    short8 vb = *(const short8*)(
                        Vt + (size_t)((h << 5) + (dt << 4) + l16) * M_DIM +
                        (wl << 5) + (ks << 5) + (quad << 3));
                    o[0][dt] =
                        __builtin_amdgcn_mfma_f32_16x16x32_bf16(pa0, vb, o[0][dt], 0, 0, 0);
                    o[1][dt] =
                        __builtin_amdgcn_mfma_f32_16x16x32_bf16(pa1, vb, o[1][dt], 0, 0, 0);
                }
            }
#pragma unroll
            for (int m = 0; m < 2; ++m)
#pragma unroll
                for (int dt = 0; dt < 2; ++dt)
#pragma unroll
                    for (int r = 0; r < 4; ++r)
                        AR[(m << 4) + (quad << 2) + r]
                          [(h << 5) + (dt << 4) + l16] = (short)f2bf(o[m][dt][r]);
        }
        __syncthreads();

        // ---------------- proj: Zf = AR @ Wp'^T + bproj (fp32)
        {
            floatx4 acc[4];
#pragma unroll
            for (int i = 0; i < 4; ++i) acc[i] = (floatx4){0.f, 0.f, 0.f, 0.f};
            mgemm4((const short*)AR, 264, a.Wp[l], 256, 0, laneRow, colbase,
                   quad, l16, acc);
            const float* bpj = a.bpj[l];
#pragma unroll
            for (int i = 0; i < 4; ++i) {
                int col = colbase + (i << 4) + l16;
                float bv = bpj[col];
#pragma unroll
                for (int r = 0; r < 4; ++r)
                    Zf[(mt << 4) + (quad << 2) + r][col] = acc[i][r] + bv;
            }
        }
        __syncthreads();

        // ---------------- LNz: ZH = bf16(LN(Z)); Zf <- LN(Z)*pw+pb
        {
            const float* pw = a.pw[l];
            const float* pb = a.pb[l];
            float4 v[4];
#pragma unroll
            for (int g4 = 0; g4 < 4; ++g4)
                v[g4] = *(const float4*)&Zf[r16][c0 + (g4 << 2)];
            float s = 0.f, ss = 0.f;
#pragma unroll
            for (int g4 = 0; g4 < 4; ++g4) {
                s += v[g4].x + v[g4].y + v[g4].z + v[g4].w;
                ss += v[g4].x * v[g4].x + v[g4].y * v[g4].y + v[g4].z * v[g4].z +
                      v[g4].w * v[g4].w;
            }
#pragma unroll
            for (int o = 1; o < 16; o <<= 1) {
                s += __shfl_xor(s, o, 64);
                ss += __shfl_xor(ss, o, 64);
            }
            float mu = s * (1.f / 256.f);
            float rs = rsqrtf(ss * (1.f / 256.f) - mu * mu + 1e-5f);
#pragma unroll
            for (int g4 = 0; g4 < 4; ++g4) {
                float4 z;
                z.x = (v[g4].x - mu) * rs;
                z.y = (v[g4].y - mu) * rs;
                z.z = (v[g4].z - mu) * rs;
                z.w = (v[g4].w - mu) * rs;
                short4v o;
                o[0] = (short)f2bf(z.x);
                o[1] = (short)f2bf(z.y);
                o[2] = (short)f2bf(z.z);
                o[3] = (short)f2bf(z.w);
                *(short4v*)&ZH[r16][c0 + (g4 << 2)] = o;
                float4 w4 = *(const float4*)&pw[c0 + (g4 << 2)];
                float4 b4 = *(const float4*)&pb[c0 + (g4 << 2)];
                float4 za;
                za.x = z.x * w4.x + b4.x;
                za.y = z.y * w4.y + b4.y;
                za.z = z.z * w4.z + b4.z;
                za.w = z.w * w4.w + b4.w;
                *(float4*)&Zf[r16][c0 + (g4 << 2)] = za;
            }
        }
        __syncthreads();

        // ---------------- m1: HH = gelu(ZH @ Wm1'^T + m1b), 128 cols/wave
        {
            floatx4 acc[8];
#pragma unroll
            for (int i = 0; i < 8; ++i) acc[i] = (floatx4){0.f, 0.f, 0.f, 0.f};
            mgemm8((const short*)ZH, 264, a.Wm1[l], 256, laneRow, g << 7,
                   quad, l16, acc);
            const float* m1b = a.m1b[l];
#pragma unroll
            for (int i = 0; i < 8; ++i) {
                int col = (g << 7) + (i << 4) + l16;
                float bv = m1b[col];
                short (*H)[264] = (col >> 8) ? QR : XH;
                int lc = col & 255;
#pragma unroll
                for (int r = 0; r < 4; ++r)
                    H[(mt << 4) + (quad << 2) + r][lc] =
                        (short)f2bf(gelu_exact(acc[i][r] + bv));
            }
        }
        __syncthreads();

        // ---------------- m2: x' = HH @ Wm2'^T + bm2 + Zf (K=512)
        {
            floatx4 acc[4];
#pragma unroll
            for (int i = 0; i < 4; ++i) acc[i] = (floatx4){0.f, 0.f, 0.f, 0.f};
            mgemm4((const short*)XH, 264, a.Wm2[l], 512, 0, laneRow, colbase,
                   quad, l16, acc);
            mgemm4((const short*)QR, 264, a.Wm2[l], 512, 256, laneRow, colbase,
                   quad, l16, acc);
            const float* b2 = a.bm2v[l];
#pragma unroll
            for (int i = 0; i < 4; ++i) {
                int col = colbase + (i << 4) + l16;
                float bv = b2[col];
#pragma unroll
                for (int r = 0; r < 4; ++r) {
                    int row = (mt << 4) + (quad << 2) + r;
                    float v = acc[i][r] + bv + Zf[row][col];
                    if (l == 0) {
                        Zf[row][col] = v;
                    } else if (row < qcnt) {
                        a.xfinal[(size_t)gp[row] * 256 + col] = v;
                    }
                }
            }
        }
        __syncthreads();
    }
}

// ======================= final: LN_post + L2 norm + transpose ==============
__global__ __launch_bounds__(256) void out_kernel(const float* __restrict__ X,
                                                  const float* __restrict__ w,
                                                  const float* __restrict__ b,
                                                  float* __restrict__ out) {
    __shared__ float tile[64][65];
    int t = threadIdx.x;
    int mo = t >> 2, q = t & 3;
    int m0 = blockIdx.x << 6;
    const float* p = X + (size_t)(m0 + mo) * C_DIM + (q << 6);
    float4 v[16];
    float s = 0.f, ss = 0.f;
#pragma unroll
    for (int c = 0; c < 16; ++c) {
        v[c] = *(const float4*)(p + c * 4);
        s += v[c].x + v[c].y + v[c].z + v[c].w;
        ss += v[c].x * v[c].x + v[c].y * v[c].y + v[c].z * v[c].z + v[c].w * v[c].w;
    }
    s += __shfl_xor(s, 1, 64); s += __shfl_xor(s, 2, 64);
    ss += __shfl_xor(ss, 1, 64); ss += __shfl_xor(ss, 2, 64);
    float mu = s * (1.f / 256.f);
    float rs = rsqrtf(ss * (1.f / 256.f) - mu * mu + 1e-5f);
    float ss2 = 0.f;
#pragma unroll
    for (int c = 0; c < 16; ++c) {
        float4 w4 = *(const float4*)&w[(q << 6) + c * 4];
        float4 b4 = *(const float4*)&b[(q << 6) + c * 4];
        v[c].x = (v[c].x - mu) * rs * w4.x + b4.x;
        v[c].y = (v[c].y - mu) * rs * w4.y + b4.y;
        v[c].z = (v[c].z - mu) * rs * w4.z + b4.z;
        v[c].w = (v[c].w - mu) * rs * w4.w + b4.w;
        ss2 += v[c].x * v[c].x + v[c].y * v[c].y + v[c].z * v[c].z + v[c].w * v[c].w;
    }
    ss2 += __shfl_xor(ss2, 1, 64); ss2 += __shfl_xor(ss2, 2, 64);
    float sc = 1.f / fmaxf(sqrtf(ss2), 1e-12f);
    for (int cc = 0; cc < 4; ++cc) {
        if (q == cc) {
#pragma unroll
            for (int c = 0; c < 16; ++c) {
                tile[mo][c * 4 + 0] = v[c].x * sc;
                tile[mo][c * 4 + 1] = v[c].y * sc;
                tile[mo][c * 4 + 2] = v[c].z * sc;
                tile[mo][c * 4 + 3] = v[c].w * sc;
            }
        }
        __syncthreads();
        for (int it = 0; it < 16; ++it) {
            int idx = it * 256 + t;
            int co = idx >> 6, mr = idx & 63;
            out[(size_t)((cc << 6) + co) * M_DIM + m0 + mr] = tile[mr][co];
        }
        __syncthreads();
    }
}

// ---------------------------------------------------------------------------
extern "C" void kernel_launch(void* const* d_in, const int* in_sizes, int n_in,
                              void* d_out, int out_size, void* d_ws, size_t ws_size,
                              hipStream_t stream) {
    const float* grd2sat = (const float*)d_in[0];
    const float* grd_x   = (const float*)d_in[1];
    const float* u       = (const float*)d_in[2];
    const float* ln_q_w  = (const float*)d_in[3];
    const float* ln_q_b  = (const float*)d_in[4];
    const float* ln_k_w  = (const float*)d_in[5];
    const float* ln_k_b  = (const float*)d_in[6];
    const float* ln_v_w  = (const float*)d_in[7];
    const float* ln_v_b  = (const float*)d_in[8];
    const float* Wq      = (const float*)d_in[9];
    const float* Wk      = (const float*)d_in[10];
    const float* Wv      = (const float*)d_in[11];
    const float* Wproj   = (const float*)d_in[12];
    const float* bproj   = (const float*)d_in[13];
    const float* ln_pre_w = (const float*)d_in[14];
    const float* ln_pre_b = (const float*)d_in[15];
    const float* Wm1     = (const float*)d_in[16];
    const float* bm1     = (const float*)d_in[17];
    const float* Wm2     = (const float*)d_in[18];
    const float* bm2     = (const float*)d_in[19];
    const float* ln_post_w = (const float*)d_in[20];
    const float* ln_post_b = (const float*)d_in[21];

    float* ws   = (float*)d_ws;
    float* yhat = ws;                        // 4 MB
    float* xcur = ws + 1048576;              // 4 MB
    float* zq   = ws + 2097152;              // 4 MB (xfinal)
    unsigned short* Ktab0 = (unsigned short*)(ws + 6291456); // 2 MB
    unsigned short* Vt0   = (unsigned short*)(ws + 6815744); // 2 MB
    unsigned short* Ktab1 = (unsigned short*)(ws + 7340032); // 2 MB
    unsigned short* Vt1   = (unsigned short*)(ws + 7864320); // 2 MB
    unsigned short* Bt    = (unsigned short*)(ws + 8388608); // 2 MB (both blocks)
    float* biasbuf = ws + 8912896;           // 2560 floats
    int*  perm    = (int*)(ws + 8915456);    // 4096 ints
    int4* chunks  = (int4*)(ws + 8919552);   // 512 int4
    int*  nchunks = (int*)(ws + 8921600);
    const size_t BS = 524288;
    const size_t OQ = 0, OKV = 65536, OP = 196608, OM1 = 262144, OM2 = 393216;

    dim3 b256(256);

    PrepArgs pa;
    pa.grd2sat = grd2sat; pa.xcur = xcur;
    pa.grd_x = grd_x;     pa.yhat = yhat;
    pa.u = u; pa.perm = perm; pa.chunks = chunks; pa.nchunks = nchunks;
    {
        int base = 0;
        for (int i = 0; i < 2; ++i) {
            int e = 6 * i;
            unsigned short* bt = Bt + i * BS;
            pa.win[e+0] = Wq + i * 65536;    pa.wout[e+0] = bt + OQ;
            pa.wlnw[e+0] = ln_q_w + i * 256; pa.wR[e+0] = 256; pa.wC[e+0] = 256;
            pa.win[e+1] = Wk + i * 65536;    pa.wout[e+1] = bt + OKV;
            pa.wlnw[e+1] = ln_k_w + i * 256; pa.wR[e+1] = 256; pa.wC[e+1] = 256;
            pa.win[e+2] = Wv + i * 65536;    pa.wout[e+2] = bt + OKV + 65536;
            pa.wlnw[e+2] = ln_v_w + i * 256; pa.wR[e+2] = 256; pa.wC[e+2] = 256;
            pa.win[e+3] = Wproj + i * 65536; pa.wout[e+3] = bt + OP;
            pa.wlnw[e+3] = nullptr;          pa.wR[e+3] = 256; pa.wC[e+3] = 256;
            pa.win[e+4] = Wm1 + i * 131072;  pa.wout[e+4] = bt + OM1;
            pa.wlnw[e+4] = ln_pre_w + i * 256; pa.wR[e+4] = 256; pa.wC[e+4] = 512;
            pa.win[e+5] = Wm2 + i * 131072;  pa.wout[e+5] = bt + OM2;
            pa.wlnw[e+5] = nullptr;          pa.wR[e+5] = 512; pa.wC[e+5] = 256;
        }
        for (int e = 0; e < 12; ++e) {
            pa.wbase[e] = base;
            base += (pa.wR[e] >> 5) * (pa.wC[e] >> 5);
        }
        pa.wbase[12] = base;  // 1024
        for (int i = 0; i < 2; ++i) {
            int jb = 5 * i;
            float* bb = biasbuf + i * 1280;
            pa.fW[jb+0] = Wq + i * 65536; pa.flnb[jb+0] = ln_q_b + i * 256;
            pa.fbase[jb+0] = nullptr; pa.fout[jb+0] = bb;
            pa.fN[jb+0] = 256; pa.fwcol[jb+0] = 0; pa.focol[jb+0] = 0;
            pa.fW[jb+1] = Wk + i * 65536; pa.flnb[jb+1] = ln_k_b + i * 256;
            pa.fbase[jb+1] = nullptr; pa.fout[jb+1] = bb + 256;
            pa.fN[jb+1] = 256; pa.fwcol[jb+1] = 0; pa.focol[jb+1] = 0;
            pa.fW[jb+2] = Wv + i * 65536; pa.flnb[jb+2] = ln_v_b + i * 256;
            pa.fbase[jb+2] = nullptr; pa.fout[jb+2] = bb + 256;
            pa.fN[jb+2] = 256; pa.fwcol[jb+2] = 0; pa.focol[jb+2] = 256;
            pa.fW[jb+3] = Wm1 + i * 131072; pa.flnb[jb+3] = ln_pre_b + i * 256;
            pa.fbase[jb+3] = bm1 + i * 512; pa.fout[jb+3] = bb + 768;
            pa.fN[jb+3] = 512; pa.fwcol[jb+3] = 0; pa.focol[jb+3] = 0;
            pa.fW[jb+4] = Wm1 + i * 131072; pa.flnb[jb+4] = ln_pre_b + i * 256;
            pa.fbase[jb+4] = bm1 + i * 512; pa.fout[jb+4] = bb + 768;
            pa.fN[jb+4] = 512; pa.fwcol[jb+4] = 256; pa.focol[jb+4] = 256;
        }
    }
    prep_kernel<<<1449, b256, 0, stream>>>(pa);

    // ---- K/V tables for both transformer blocks
    GJ jkv0 = {};
    jkv0.A = yhat; jkv0.Bt = Bt + OKV; jkv0.bias = biasbuf + 256;
    jkv0.out = Ktab0; jkv0.out2 = Vt0; jkv0.K = 256; jkv0.N = 512;
    GJ jkv1 = {};
    jkv1.A = yhat; jkv1.Bt = Bt + BS + OKV; jkv1.bias = biasbuf + 1280 + 256;
    jkv1.out = Ktab1; jkv1.out2 = Vt1; jkv1.K = 256; jkv1.N = 512;
    kv_kernel<<<dim3(128, 16), b256, 0, stream>>>(jkv0, jkv1);

    // ---- mega chunk kernel v3 (512 threads)
    MegaArgs ma;
    ma.xcur = xcur; ma.perm = perm; ma.chunks = chunks; ma.nchunks = nchunks;
    ma.xfinal = zq;
    for (int i = 0; i < 2; ++i) {
        const unsigned short* bt = Bt + i * BS;
        ma.Wq[i] = bt + OQ; ma.Wp[i] = bt + OP;
        ma.Wm1[i] = bt + OM1; ma.Wm2[i] = bt + OM2;
        ma.Ktb[i] = i ? Ktab1 : Ktab0; ma.Vtb[i] = i ? Vt1 : Vt0;
        ma.qb[i] = biasbuf + i * 1280;
        ma.m1b[i] = biasbuf + i * 1280 + 768;
        ma.bpj[i] = bproj + i * 256;
        ma.bm2v[i] = bm2 + i * 256;
        ma.pw[i] = ln_pre_w + i * 256;
        ma.pb[i] = ln_pre_b + i * 256;
    }
    ma.aw = ln_post_w; ma.ab = ln_post_b;  // block 0 ln_post for layer-1 LN2
    mega_kernel<<<288, dim3(512), 0, stream>>>(ma);

    out_kernel<<<64, b256, 0, stream>>>(zq, ln_post_w + 256, ln_post_b + 256,
                                        (float*)d_out);
}

// Round 4
// 207.104 us; speedup vs baseline: 1.3902x; 1.2258x over previous
//
#include <hip/hip_runtime.h>
#include <math.h>

// ---------------------------------------------------------------------------
// CrossViewAttention — R8: mega v4 — 2m×2n wave tiles + batched B-preload
// into registers (one latency exposure per GEMM), launch_bounds(512).
// B=1, C=256, M=4096, W=128, H=32, BLOCKS=2, HEADS=8, DH=32
// ---------------------------------------------------------------------------

#define C_DIM 256
#define M_DIM 4096
#define W_DIM 128
#define H_DIM 32
#define ATT_SCALE 0.17677669529663687f  // 1/sqrt(32)

typedef __attribute__((ext_vector_type(8))) short short8;
typedef __attribute__((ext_vector_type(4))) short short4v;
typedef __attribute__((ext_vector_type(4))) float floatx4;

__device__ __forceinline__ unsigned short f2bf(float f) {
    unsigned u = __float_as_uint(f);
    unsigned r = (u + 0x7fffu + ((u >> 16) & 1u)) >> 16;
    return (unsigned short)r;
}
__device__ __forceinline__ float gelu_exact(float x) {
    return 0.5f * x * (1.0f + erff(x * 0.70710678118654752f));
}

// ======================= mega prep kernel ==================================
struct PrepArgs {
    const float* grd2sat; float* xcur;
    const float* grd_x;   float* yhat;
    const float* u; int* perm; int4* chunks; int* nchunks;
    const float* win[12]; unsigned short* wout[12]; const float* wlnw[12];
    int wR[12], wC[12], wbase[13];
    const float* fW[10]; const float* flnb[10]; const float* fbase[10];
    float* fout[10];
    int fN[10], fwcol[10], focol[10];
};

__global__ __launch_bounds__(256) void prep_kernel(PrepArgs a) {
    __shared__ float smemf[9024];
    int b = blockIdx.x, t = threadIdx.x;
    if (b < 256) {
        float (*tile)[65] = (float(*)[65])smemf;
        int m0 = (b & 63) << 6, c0 = (b >> 6) << 6;
        for (int it = 0; it < 16; ++it) {
            int idx = it * 256 + t;
            int co = idx >> 6, mo = idx & 63;
            tile[co][mo] = a.grd2sat[(size_t)(c0 + co) * M_DIM + m0 + mo];
        }
        __syncthreads();
        for (int it = 0; it < 16; ++it) {
            int idx = it * 256 + t;
            int mo = idx >> 6, co = idx & 63;
            a.xcur[(size_t)(m0 + mo) * C_DIM + c0 + co] = tile[co][mo];
        }
    } else if (b < 384) {
        int idx = b - 256;
        int h = idx & 31, w0 = (idx >> 5) << 5;
        float (*tile)[33] = (float(*)[33])smemf;
        float (*ps)[32] = (float(*)[32])(smemf + 8448);
        float (*pss)[32] = (float(*)[32])(smemf + 8704);
        float* mu_s = smemf + 8960;
        float* rs_s = smemf + 8992;
        int wo = t & 31, cb = t >> 5;
        for (int it = 0; it < 32; ++it) {
            int c = it * 8 + cb;
            tile[c][wo] = a.grd_x[(size_t)c * (H_DIM * W_DIM) + h * W_DIM + w0 + wo];
        }
        __syncthreads();
        {
            int w = t & 31, part = t >> 5;
            float s = 0.f, ss = 0.f;
            for (int c = part * 32; c < part * 32 + 32; ++c) {
                float x = tile[c][w];
                s += x; ss += x * x;
            }
            ps[part][w] = s; pss[part][w] = ss;
        }
        __syncthreads();
        if (t < 32) {
            float s = 0.f, ss = 0.f;
            for (int p = 0; p < 8; ++p) { s += ps[p][t]; ss += pss[p][t]; }
            float mu = s * (1.f / 256.f);
            float var = ss * (1.f / 256.f) - mu * mu;
            mu_s[t] = mu;
            rs_s[t] = rsqrtf(var + 1e-5f);
        }
        __syncthreads();
        for (int jj = 0; jj < 32; ++jj) {
            float mu = mu_s[jj], rs = rs_s[jj];
            a.yhat[((size_t)(w0 + jj) * H_DIM + h) * C_DIM + t] =
                (tile[t][jj] - mu) * rs;
        }
    } else if (b < 1408) {
        int wI = b - 384;
        int e = 0;
        while (wI >= a.wbase[e + 1]) ++e;
        int tl = wI - a.wbase[e];
        int tilesC = a.wC[e] >> 5;
        int tr = tl / tilesC, tc = tl - tr * tilesC;
        int r0 = tr << 5, c0 = tc << 5;
        const float* in = a.win[e];
        unsigned short* out = a.wout[e];
        const float* lnw = a.wlnw[e];
        int R = a.wR[e], Cc = a.wC[e];
        float (*tile)[33] = (float(*)[33])smemf;
        int rl = t >> 3, cq = (t & 7) << 2;
        float4 v = *(const float4*)&in[(size_t)(r0 + rl) * Cc + c0 + cq];
        if (lnw) {
            float s = lnw[r0 + rl];
            v.x *= s; v.y *= s; v.z *= s; v.w *= s;
        }
        tile[rl][cq + 0] = v.x;
        tile[rl][cq + 1] = v.y;
        tile[rl][cq + 2] = v.z;
        tile[rl][cq + 3] = v.w;
        __syncthreads();
        int cl = t >> 3, rq = (t & 7) << 2;
        ushort4 o;
        o.x = f2bf(tile[rq + 0][cl]);
        o.y = f2bf(tile[rq + 1][cl]);
        o.z = f2bf(tile[rq + 2][cl]);
        o.w = f2bf(tile[rq + 3][cl]);
        *(ushort4*)&out[(size_t)(c0 + cl) * R + r0 + rq] = o;
    } else if (b < 1448) {
        int idx = b - 1408;            // 0..39
        int jj = idx >> 2, part = idx & 3;
        int N = a.fN[jj];
        int c = t & 63, kp = t >> 6;   // 4 k-parts of 64
        int wcol = a.fwcol[jj] + (part << 6) + c;
        const float* W = a.fW[jj];
        const float* lb = a.flnb[jj];
        float s = 0.f;
        for (int k = kp * 64; k < kp * 64 + 64; ++k)
            s += lb[k] * W[(size_t)k * N + wcol];
        smemf[(kp << 6) + c] = s;
        __syncthreads();
        if (t < 64) {
            float tot = smemf[t] + smemf[64 + t] + smemf[128 + t] + smemf[192 + t];
            int ocol = a.focol[jj] + (part << 6) + t;
            if (a.fbase[jj]) tot += a.fbase[jj][a.fwcol[jj] + (part << 6) + t];
            a.fout[jj][ocol] = tot;
        }
    } else {
        int* hist = (int*)smemf;
        int* cur = (int*)smemf + 128;
        unsigned short* wlb = (unsigned short*)((int*)smemf + 256);
        if (t < 128) hist[t] = 0;
        __syncthreads();
        for (int it = 0; it < 16; ++it) {
            int m = it * 256 + t;
            int wl = (int)floorf(a.u[m]);
            wl = max(0, min(wl, 126));
            wlb[m] = (unsigned short)wl;
            atomicAdd(&hist[wl], 1);
        }
        __syncthreads();
        if (t == 0) {
            int run = 0, nc = 0;
            for (int bkt = 0; bkt < 127; ++bkt) {
                int c = hist[bkt];
                cur[bkt] = run;
                int q0 = run;
                while (c > 0) {
                    int take = min(c, 32);
                    a.chunks[nc] = make_int4(bkt, q0, take, 0);
                    ++nc; q0 += take; c -= take;
                }
                run += hist[bkt];
            }
            *a.nchunks = nc;
        }
        __syncthreads();
        for (int it = 0; it < 16; ++it) {
            int m = it * 256 + t;
            int wl = wlb[m];
            int pos = atomicAdd(&cur[wl], 1);
            a.perm[pos] = m;
        }
    }
}

// ======================= KV GEMM ===========================================
struct GJ {
    const void* A; const unsigned short* Bt;
    const float* bias;
    void* out; unsigned short* out2;
    int K, N;
};

__device__ __forceinline__ void gemm_core_kv(const GJ& j, short (*As)[264],
                                             short (*Bs)[264], int bm, int by) {
    int t = threadIdx.x;
    int bn = by << 6;
    int wv = t >> 6, lane = t & 63;
    int mt = wv & 1, nt0 = (wv >> 1) << 1;
    int quad = lane >> 4, l16 = lane & 15;
    floatx4 acc0 = {0.f, 0.f, 0.f, 0.f};
    floatx4 acc1 = {0.f, 0.f, 0.f, 0.f};
    {
        int ar = t >> 3, cq = (t & 7) << 2;
        const float* ap = (const float*)j.A + (size_t)(bm + ar) * 256 + cq;
        float4 v[8];
#pragma unroll
        for (int g = 0; g < 8; ++g) v[g] = *(const float4*)(ap + g * 32);
#pragma unroll
        for (int g = 0; g < 8; ++g) {
            short4v o;
            o[0] = (short)f2bf(v[g].x);
            o[1] = (short)f2bf(v[g].y);
            o[2] = (short)f2bf(v[g].z);
            o[3] = (short)f2bf(v[g].w);
            *(short4v*)&As[ar][cq + g * 32] = o;
        }
    }
    {
        int br = t >> 2, cq2 = (t & 3) << 3;
        const unsigned short* bp = j.Bt + (size_t)(bn + br) * 256 + cq2;
#pragma unroll
        for (int g = 0; g < 8; ++g)
            *(short8*)&Bs[br][cq2 + g * 32] = *(const short8*)(bp + g * 32);
    }
    __syncthreads();
#pragma unroll
    for (int k0 = 0; k0 < 8; ++k0) {
        short8 aa = *(const short8*)&As[(mt << 4) + l16][(k0 << 5) + (quad << 3)];
        short8 b0 = *(const short8*)&Bs[(nt0 << 4) + l16][(k0 << 5) + (quad << 3)];
        short8 b1 =
            *(const short8*)&Bs[((nt0 + 1) << 4) + l16][(k0 << 5) + (quad << 3)];
        acc0 = __builtin_amdgcn_mfma_f32_16x16x32_bf16(aa, b0, acc0, 0, 0, 0);
        acc1 = __builtin_amdgcn_mfma_f32_16x16x32_bf16(aa, b1, acc1, 0, 0, 0);
    }
#pragma unroll
    for (int jj = 0; jj < 2; ++jj) {
        const floatx4 accv = jj ? acc1 : acc0;
        int col = bn + ((nt0 + jj) << 4) + l16;
        float bv = j.bias[col];
#pragma unroll
        for (int r = 0; r < 4; ++r) {
            int row = bm + (mt << 4) + (quad << 2) + r;
            float v = accv[r] + bv;
            if (col < 256)
                ((unsigned short*)j.out)[(size_t)row * 256 + col] = f2bf(v);
            else
                j.out2[(size_t)(col - 256) * M_DIM + row] = f2bf(v);
        }
    }
}

__global__ __launch_bounds__(256) void kv_kernel(GJ j0, GJ j1) {
    __shared__ short As[32][264];
    __shared__ short Bs[64][264];
    int bm = blockIdx.x << 5;
    if ((int)blockIdx.y < 8)
        gemm_core_kv(j0, As, Bs, bm, blockIdx.y);
    else
        gemm_core_kv(j1, As, Bs, bm, blockIdx.y - 8);
}

// ======================= mega chunk kernel v4 ==============================
struct MegaArgs {
    const float* xcur;
    const int* perm; const int4* chunks; const int* nchunks;
    float* xfinal;
    const unsigned short* Wq[2]; const unsigned short* Wp[2];
    const unsigned short* Wm1[2]; const unsigned short* Wm2[2];
    const unsigned short* Ktb[2]; const unsigned short* Vtb[2];
    const float* qb[2]; const float* m1b[2];
    const float* bpj[2]; const float* bm2v[2];
    const float* pw[2]; const float* pb[2];
    const float* aw; const float* ab;  // ln_post[0] for layer-1 LN2
};

// Batched B-preload: 16 fragments (8 k0-steps x 2 n-tiles) = 64 VGPRs.
struct BPre { short8 b[8][2]; };

__device__ __forceinline__ void preloadB(const unsigned short* Bt, int Kstride,
                                         int koff, int colw, int l16, int quad,
                                         BPre& P) {
    const unsigned short* bp =
        Bt + (size_t)(colw + l16) * Kstride + koff + (quad << 3);
#pragma unroll
    for (int k0 = 0; k0 < 8; ++k0)
#pragma unroll
        for (int ni = 0; ni < 2; ++ni)
            P.b[k0][ni] =
                *(const short8*)(bp + (size_t)(ni << 4) * Kstride + (k0 << 5));
}

// 32x32 wave tile: acc[mi][ni] over A(32 rows in LDS) x preloaded B.
__device__ __forceinline__ void mfma32t(const short* As, int lda, const BPre& P,
                                        int l16, int quad, floatx4 acc[2][2]) {
    const short* ap = As + (size_t)l16 * lda + (quad << 3);
#pragma unroll
    for (int k0 = 0; k0 < 8; ++k0) {
        short8 a0 = *(const short8*)(ap + (k0 << 5));
        short8 a1 = *(const short8*)(ap + (size_t)16 * lda + (k0 << 5));
        acc[0][0] = __builtin_amdgcn_mfma_f32_16x16x32_bf16(a0, P.b[k0][0], acc[0][0], 0, 0, 0);
        acc[0][1] = __builtin_amdgcn_mfma_f32_16x16x32_bf16(a0, P.b[k0][1], acc[0][1], 0, 0, 0);
        acc[1][0] = __builtin_amdgcn_mfma_f32_16x16x32_bf16(a1, P.b[k0][0], acc[1][0], 0, 0, 0);
        acc[1][1] = __builtin_amdgcn_mfma_f32_16x16x32_bf16(a1, P.b[k0][1], acc[1][1], 0, 0, 0);
    }
}

#define ZACC(A) \
    { A[0][0] = (floatx4){0.f,0.f,0.f,0.f}; A[0][1] = (floatx4){0.f,0.f,0.f,0.f}; \
      A[1][0] = (floatx4){0.f,0.f,0.f,0.f}; A[1][1] = (floatx4){0.f,0.f,0.f,0.f}; }

// LDS layout (bytes):
//  [0,      16896)  XH short[32][264]  (stage1->Q) / HH0 (m1 cols 0-255)
//  [16896,  33792)  QR short[32][264]  (Q->attn)   / HH1 (m1 cols 256-511)
//  [33792,  50688)  ZH short[32][264]  (LNz->m1)
//  [50688,  67584)  AR short[32][264]  (attn->proj)
//  [67584, 100864)  Zf float[32][260]  (proj z; residual; x' in-place)
//  [100864,137728)  PB short[8][32][72] (per-wave softmax P slot)
//  [137728,137856)  gperm int[32]
__global__ __launch_bounds__(512) void mega_kernel(MegaArgs a) {
    __shared__ __align__(16) char smem[137856];
    short (*XH)[264] = (short(*)[264])(smem);
    short (*QR)[264] = (short(*)[264])(smem + 16896);
    short (*ZH)[264] = (short(*)[264])(smem + 33792);
    short (*AR)[264] = (short(*)[264])(smem + 50688);
    float (*Zf)[260] = (float(*)[260])(smem + 67584);
    short (*PB)[32][72] = (short(*)[32][72])(smem + 100864);
    int* gp = (int*)(smem + 137728);

    if ((int)blockIdx.x >= *a.nchunks) return;
    int4 cd = a.chunks[blockIdx.x];
    int wl = cd.x, qstart = cd.y, qcnt = cd.z;
    int t = threadIdx.x;
    if (t < 32) gp[t] = (t < qcnt) ? a.perm[qstart + t] : a.perm[qstart];
    __syncthreads();

    int wv = t >> 6, lane = t & 63, quad = lane >> 4, l16 = lane & 15;
    int colw = wv << 5;                     // this wave's 32-col slice
    int r16 = t >> 4, c0 = (t & 15) << 4;   // LN mapping: 16 lanes/row

#pragma unroll 1
    for (int l = 0; l < 2; ++l) {
        // ---------------- stage1: XH = LN(x) (l=1: LN->ln_post0 affine->LN)
        BPre Pq;
        preloadB(a.Wq[l], 256, 0, colw, l16, quad, Pq);  // issue early
        {
            float4 v[4];
            if (l == 0) {
                const float* xp = a.xcur + (size_t)gp[r16] * 256 + c0;
#pragma unroll
                for (int g4 = 0; g4 < 4; ++g4)
                    v[g4] = *(const float4*)(xp + (g4 << 2));
            } else {
#pragma unroll
                for (int g4 = 0; g4 < 4; ++g4)
                    v[g4] = *(const float4*)&Zf[r16][c0 + (g4 << 2)];
            }
            float s = 0.f, ss = 0.f;
#pragma unroll
            for (int g4 = 0; g4 < 4; ++g4) {
                s += v[g4].x + v[g4].y + v[g4].z + v[g4].w;
                ss += v[g4].x * v[g4].x + v[g4].y * v[g4].y + v[g4].z * v[g4].z +
                      v[g4].w * v[g4].w;
            }
#pragma unroll
            for (int o = 1; o < 16; o <<= 1) {
                s += __shfl_xor(s, o, 64);
                ss += __shfl_xor(ss, o, 64);
            }
            float mu = s * (1.f / 256.f);
            float rs = rsqrtf(ss * (1.f / 256.f) - mu * mu + 1e-5f);
#pragma unroll
            for (int g4 = 0; g4 < 4; ++g4) {
                v[g4].x = (v[g4].x - mu) * rs;
                v[g4].y = (v[g4].y - mu) * rs;
                v[g4].z = (v[g4].z - mu) * rs;
                v[g4].w = (v[g4].w - mu) * rs;
            }
            if (l == 1) {
                float s2 = 0.f, ss2 = 0.f;
#pragma unroll
                for (int g4 = 0; g4 < 4; ++g4) {
                    float4 w4 = *(const float4*)&a.aw[c0 + (g4 << 2)];
                    float4 b4 = *(const float4*)&a.ab[c0 + (g4 << 2)];
                    v[g4].x = v[g4].x * w4.x + b4.x;
                    v[g4].y = v[g4].y * w4.y + b4.y;
                    v[g4].z = v[g4].z * w4.z + b4.z;
                    v[g4].w = v[g4].w * w4.w + b4.w;
                    s2 += v[g4].x + v[g4].y + v[g4].z + v[g4].w;
                    ss2 += v[g4].x * v[g4].x + v[g4].y * v[g4].y +
                           v[g4].z * v[g4].z + v[g4].w * v[g4].w;
                }
#pragma unroll
                for (int o = 1; o < 16; o <<= 1) {
                    s2 += __shfl_xor(s2, o, 64);
                    ss2 += __shfl_xor(ss2, o, 64);
                }
                float mu2 = s2 * (1.f / 256.f);
                float rs2 = rsqrtf(ss2 * (1.f / 256.f) - mu2 * mu2 + 1e-5f);
#pragma unroll
                for (int g4 = 0; g4 < 4; ++g4) {
                    v[g4].x = (v[g4].x - mu2) * rs2;
                    v[g4].y = (v[g4].y - mu2) * rs2;
                    v[g4].z = (v[g4].z - mu2) * rs2;
                    v[g4].w = (v[g4].w - mu2) * rs2;
                }
            }
#pragma unroll
            for (int g4 = 0; g4 < 4; ++g4) {
                short4v o;
                o[0] = (short)f2bf(v[g4].x);
                o[1] = (short)f2bf(v[g4].y);
                o[2] = (short)f2bf(v[g4].z);
                o[3] = (short)f2bf(v[g4].w);
                *(short4v*)&XH[r16][c0 + (g4 << 2)] = o;
            }
        }
        __syncthreads();

        // ---------------- Q: QR = XH @ Wq'^T + qb
        // (attention K/V preloads issued here, hidden under the Q MFMAs)
        short8 kb[4], vfrag[2][2];
        {
            const unsigned short* Kt = a.Ktb[l];
            const unsigned short* Vt = a.Vtb[l];
            int h = wv;
#pragma unroll
            for (int nt = 0; nt < 4; ++nt)
                kb[nt] = *(const short8*)(
                    Kt + (size_t)((wl << 5) + (nt << 4) + l16) * 256 +
                    (h << 5) + (quad << 3));
#pragma unroll
            for (int ks = 0; ks < 2; ++ks)
#pragma unroll
                for (int dt = 0; dt < 2; ++dt)
                    vfrag[ks][dt] = *(const short8*)(
                        Vt + (size_t)((h << 5) + (dt << 4) + l16) * M_DIM +
                        (wl << 5) + (ks << 5) + (quad << 3));
        }
        {
            floatx4 acc[2][2];
            ZACC(acc);
            mfma32t((const short*)XH, 264, Pq, l16, quad, acc);
            const float* qb = a.qb[l];
#pragma unroll
            for (int ni = 0; ni < 2; ++ni) {
                int col = colw + (ni << 4) + l16;
                float bv = qb[col];
#pragma unroll
                for (int mi = 0; mi < 2; ++mi)
#pragma unroll
                    for (int r = 0; r < 4; ++r)
                        QR[(mi << 4) + (quad << 2) + r][col] =
                            (short)f2bf(acc[mi][ni][r] + bv);
            }
        }
        __syncthreads();

        // ---------------- attention: one head per wave, in-wave softmax
        BPre Pp;
        {
            int h = wv;
            short8 aq0 = *(const short8*)&QR[l16][(h << 5) + (quad << 3)];
            short8 aq1 = *(const short8*)&QR[16 + l16][(h << 5) + (quad << 3)];
            floatx4 c[2][4];
#pragma unroll
            for (int nt = 0; nt < 4; ++nt) {
                floatx4 z = {0.f, 0.f, 0.f, 0.f};
                c[0][nt] = __builtin_amdgcn_mfma_f32_16x16x32_bf16(aq0, kb[nt], z, 0, 0, 0);
                c[1][nt] = __builtin_amdgcn_mfma_f32_16x16x32_bf16(aq1, kb[nt], z, 0, 0, 0);
            }
            floatx4 ri[2];
#pragma unroll
            for (int m = 0; m < 2; ++m) {
#pragma unroll
                for (int nt = 0; nt < 4; ++nt) {
                    floatx4 e;
#pragma unroll
                    for (int r = 0; r < 4; ++r)
                        e[r] = __expf(c[m][nt][r] * ATT_SCALE);
                    c[m][nt] = e;
                }
                floatx4 s4 = c[m][0] + c[m][1] + c[m][2] + c[m][3];
#pragma unroll
                for (int r = 0; r < 4; ++r) {
                    float s = s4[r];
                    s += __shfl_xor(s, 1, 64);
                    s += __shfl_xor(s, 2, 64);
                    s += __shfl_xor(s, 4, 64);
                    s += __shfl_xor(s, 8, 64);
                    ri[m][r] = 1.f / s;
                }
            }
#pragma unroll
            for (int m = 0; m < 2; ++m)
#pragma unroll
                for (int nt = 0; nt < 4; ++nt)
#pragma unroll
                    for (int r = 0; r < 4; ++r)
                        PB[wv][(m << 4) + (quad << 2) + r][(nt << 4) + l16] =
                            (short)f2bf(c[m][nt][r] * ri[m][r]);
            __threadfence_block();
            // proj B preload hidden under PV
            preloadB(a.Wp[l], 256, 0, colw, l16, quad, Pp);
            floatx4 o[2][2];
#pragma unroll
            for (int m = 0; m < 2; ++m)
#pragma unroll
                for (int dt = 0; dt < 2; ++dt)
                    o[m][dt] = (floatx4){0.f, 0.f, 0.f, 0.f};
#pragma unroll
            for (int ks = 0; ks < 2; ++ks) {
                short8 pa0 =
                    *(const short8*)&PB[wv][l16][(ks << 5) + (quad << 3)];
                short8 pa1 =
                    *(const short8*)&PB[wv][16 + l16][(ks << 5) + (quad << 3)];
#pragma unroll
                for (int dt = 0; dt < 2; ++dt) {
                    o[0][dt] = __builtin_amdgcn_mfma_f32_16x16x32_bf16(
                        pa0, vfrag[ks][dt], o[0][dt], 0, 0, 0);
                    o[1][dt] = __builtin_amdgcn_mfma_f32_16x16x32_bf16(
                        pa1, vfrag[ks][dt], o[1][dt], 0, 0, 0);
                }
            }
            int h5 = wv << 5;
#pragma unroll
            for (int m = 0; m < 2; ++m)
#pragma unroll
                for (int dt = 0; dt < 2; ++dt)
#pragma unroll
                    for (int r = 0; r < 4; ++r)
                        AR[(m << 4) + (quad << 2) + r]
                          [h5 + (dt << 4) + l16] = (short)f2bf(o[m][dt][r]);
        }
        __syncthreads();

        // ---------------- proj: Zf = AR @ Wp'^T + bproj (fp32)
        {
            floatx4 acc[2][2];
            ZACC(acc);
            mfma32t((const short*)AR, 264, Pp, l16, quad, acc);
            const float* bpj = a.bpj[l];
#pragma unroll
            for (int ni = 0; ni < 2; ++ni) {
                int col = colw + (ni << 4) + l16;
                float bv = bpj[col];
#pragma unroll
                for (int mi = 0; mi < 2; ++mi)
#pragma unroll
                    for (int r = 0; r < 4; ++r)
                        Zf[(mi << 4) + (quad << 2) + r][col] = acc[mi][ni][r] + bv;
            }
        }
        __syncthreads();

        // ---------------- LNz: ZH = bf16(LN(Z)); Zf <- LN(Z)*pw+pb
        BPre Pm1a;
        preloadB(a.Wm1[l], 256, 0, colw, l16, quad, Pm1a);
        {
            const float* pw = a.pw[l];
            const float* pb = a.pb[l];
            float4 v[4];
#pragma unroll
            for (int g4 = 0; g4 < 4; ++g4)
                v[g4] = *(const float4*)&Zf[r16][c0 + (g4 << 2)];
            float s = 0.f, ss = 0.f;
#pragma unroll
            for (int g4 = 0; g4 < 4; ++g4) {
                s += v[g4].x + v[g4].y + v[g4].z + v[g4].w;
                ss += v[g4].x * v[g4].x + v[g4].y * v[g4].y + v[g4].z * v[g4].z +
                      v[g4].w * v[g4].w;
            }
#pragma unroll
            for (int o = 1; o < 16; o <<= 1) {
                s += __shfl_xor(s, o, 64);
                ss += __shfl_xor(ss, o, 64);
            }
            float mu = s * (1.f / 256.f);
            float rs = rsqrtf(ss * (1.f / 256.f) - mu * mu + 1e-5f);
#pragma unroll
            for (int g4 = 0; g4 < 4; ++g4) {
                float4 z;
                z.x = (v[g4].x - mu) * rs;
                z.y = (v[g4].y - mu) * rs;
                z.z = (v[g4].z - mu) * rs;
                z.w = (v[g4].w - mu) * rs;
                short4v o;
                o[0] = (short)f2bf(z.x);
                o[1] = (short)f2bf(z.y);
                o[2] = (short)f2bf(z.z);
                o[3] = (short)f2bf(z.w);
                *(short4v*)&ZH[r16][c0 + (g4 << 2)] = o;
                float4 w4 = *(const float4*)&pw[c0 + (g4 << 2)];
                float4 b4 = *(const float4*)&pb[c0 + (g4 << 2)];
                float4 za;
                za.x = z.x * w4.x + b4.x;
                za.y = z.y * w4.y + b4.y;
                za.z = z.z * w4.z + b4.z;
                za.w = z.w * w4.w + b4.w;
                *(float4*)&Zf[r16][c0 + (g4 << 2)] = za;
            }
        }
        __syncthreads();

        // ---------------- m1: gelu(ZH @ Wm1'^T + m1b) -> HH0(XH), HH1(QR)
        const float* m1b = a.m1b[l];
        BPre Pm2a;
        {
            floatx4 acc[2][2];
            ZACC(acc);
            mfma32t((const short*)ZH, 264, Pm1a, l16, quad, acc);
            BPre Pm1b;
            preloadB(a.Wm1[l] + (size_t)256 * 256, 256, 0, colw, l16, quad, Pm1b);
#pragma unroll
            for (int ni = 0; ni < 2; ++ni) {
                int col = colw + (ni << 4) + l16;
                float bv = m1b[col];
#pragma unroll
                for (int mi = 0; mi < 2; ++mi)
#pragma unroll
                    for (int r = 0; r < 4; ++r)
                        XH[(mi << 4) + (quad << 2) + r][col] =
                            (short)f2bf(gelu_exact(acc[mi][ni][r] + bv));
            }
            floatx4 acc2[2][2];
            ZACC(acc2);
            mfma32t((const short*)ZH, 264, Pm1b, l16, quad, acc2);
            preloadB(a.Wm2[l], 512, 0, colw, l16, quad, Pm2a);
#pragma unroll
            for (int ni = 0; ni < 2; ++ni) {
                int col = colw + (ni << 4) + l16;
                float bv = m1b[256 + col];
#pragma unroll
                for (int mi = 0; mi < 2; ++mi)
#pragma unroll
                    for (int r = 0; r < 4; ++r)
                        QR[(mi << 4) + (quad << 2) + r][col] =
                            (short)f2bf(gelu_exact(acc2[mi][ni][r] + bv));
            }
        }
        __syncthreads();

        // ---------------- m2: x' = HH @ Wm2'^T + bm2 + Zf (K=512)
        {
            floatx4 macc[2][2];
            ZACC(macc);
            mfma32t((const short*)XH, 264, Pm2a, l16, quad, macc);
            BPre Pm2b;
            preloadB(a.Wm2[l], 512, 256, colw, l16, quad, Pm2b);
            mfma32t((const short*)QR, 264, Pm2b, l16, quad, macc);
            const float* b2 = a.bm2v[l];
#pragma unroll
            for (int ni = 0; ni < 2; ++ni) {
                int col = colw + (ni << 4) + l16;
                float bv = b2[col];
#pragma unroll
                for (int mi = 0; mi < 2; ++mi)
#pragma unroll
                    for (int r = 0; r < 4; ++r) {
                        int row = (mi << 4) + (quad << 2) + r;
                        float v = macc[mi][ni][r] + bv + Zf[row][col];
                        if (l == 0) {
                            Zf[row][col] = v;
                        } else if (row < qcnt) {
                            a.xfinal[(size_t)gp[row] * 256 + col] = v;
                        }
                    }
            }
        }
        __syncthreads();
    }
}

// ======================= final: LN_post + L2 norm + transpose ==============
__global__ __launch_bounds__(256) void out_kernel(const float* __restrict__ X,
                                                  const float* __restrict__ w,
                                                  const float* __restrict__ b,
                                                  float* __restrict__ out) {
    __shared__ float tile[64][65];
    int t = threadIdx.x;
    int mo = t >> 2, q = t & 3;
    int m0 = blockIdx.x << 6;
    const float* p = X + (size_t)(m0 + mo) * C_DIM + (q << 6);
    float4 v[16];
    float s = 0.f, ss = 0.f;
#pragma unroll
    for (int c = 0; c < 16; ++c) {
        v[c] = *(const float4*)(p + c * 4);
        s += v[c].x + v[c].y + v[c].z + v[c].w;
        ss += v[c].x * v[c].x + v[c].y * v[c].y + v[c].z * v[c].z + v[c].w * v[c].w;
    }
    s += __shfl_xor(s, 1, 64); s += __shfl_xor(s, 2, 64);
    ss += __shfl_xor(ss, 1, 64); ss += __shfl_xor(ss, 2, 64);
    float mu = s * (1.f / 256.f);
    float rs = rsqrtf(ss * (1.f / 256.f) - mu * mu + 1e-5f);
    float ss2 = 0.f;
#pragma unroll
    for (int c = 0; c < 16; ++c) {
        float4 w4 = *(const float4*)&w[(q << 6) + c * 4];
        float4 b4 = *(const float4*)&b[(q << 6) + c * 4];
        v[c].x = (v[c].x - mu) * rs * w4.x + b4.x;
        v[c].y = (v[c].y - mu) * rs * w4.y + b4.y;
        v[c].z = (v[c].z - mu) * rs * w4.z + b4.z;
        v[c].w = (v[c].w - mu) * rs * w4.w + b4.w;
        ss2 += v[c].x * v[c].x + v[c].y * v[c].y + v[c].z * v[c].z + v[c].w * v[c].w;
    }
    ss2 += __shfl_xor(ss2, 1, 64); ss2 += __shfl_xor(ss2, 2, 64);
    float sc = 1.f / fmaxf(sqrtf(ss2), 1e-12f);
    for (int cc = 0; cc < 4; ++cc) {
        if (q == cc) {
#pragma unroll
            for (int c = 0; c < 16; ++c) {
                tile[mo][c * 4 + 0] = v[c].x * sc;
                tile[mo][c * 4 + 1] = v[c].y * sc;
                tile[mo][c * 4 + 2] = v[c].z * sc;
                tile[mo][c * 4 + 3] = v[c].w * sc;
            }
        }
        __syncthreads();
        for (int it = 0; it < 16; ++it) {
            int idx = it * 256 + t;
            int co = idx >> 6, mr = idx & 63;
            out[(size_t)((cc << 6) + co) * M_DIM + m0 + mr] = tile[mr][co];
        }
        __syncthreads();
    }
}

// ---------------------------------------------------------------------------
extern "C" void kernel_launch(void* const* d_in, const int* in_sizes, int n_in,
                              void* d_out, int out_size, void* d_ws, size_t ws_size,
                              hipStream_t stream) {
    const float* grd2sat = (const float*)d_in[0];
    const float* grd_x   = (const float*)d_in[1];
    const float* u       = (const float*)d_in[2];
    const float* ln_q_w  = (const float*)d_in[3];
    const float* ln_q_b  = (const float*)d_in[4];
    const float* ln_k_w  = (const float*)d_in[5];
    const float* ln_k_b  = (const float*)d_in[6];
    const float* ln_v_w  = (const float*)d_in[7];
    const float* ln_v_b  = (const float*)d_in[8];
    const float* Wq      = (const float*)d_in[9];
    const float* Wk      = (const float*)d_in[10];
    const float* Wv      = (const float*)d_in[11];
    const float* Wproj   = (const float*)d_in[12];
    const float* bproj   = (const float*)d_in[13];
    const float* ln_pre_w = (const float*)d_in[14];
    const float* ln_pre_b = (const float*)d_in[15];
    const float* Wm1     = (const float*)d_in[16];
    const float* bm1     = (const float*)d_in[17];
    const float* Wm2     = (const float*)d_in[18];
    const float* bm2     = (const float*)d_in[19];
    const float* ln_post_w = (const float*)d_in[20];
    const float* ln_post_b = (const float*)d_in[21];

    float* ws   = (float*)d_ws;
    float* yhat = ws;                        // 4 MB
    float* xcur = ws + 1048576;              // 4 MB
    float* zq   = ws + 2097152;              // 4 MB (xfinal)
    unsigned short* Ktab0 = (unsigned short*)(ws + 6291456); // 2 MB
    unsigned short* Vt0   = (unsigned short*)(ws + 6815744); // 2 MB
    unsigned short* Ktab1 = (unsigned short*)(ws + 7340032); // 2 MB
    unsigned short* Vt1   = (unsigned short*)(ws + 7864320); // 2 MB
    unsigned short* Bt    = (unsigned short*)(ws + 8388608); // 2 MB (both blocks)
    float* biasbuf = ws + 8912896;           // 2560 floats
    int*  perm    = (int*)(ws + 8915456);    // 4096 ints
    int4* chunks  = (int4*)(ws + 8919552);   // 512 int4
    int*  nchunks = (int*)(ws + 8921600);
    const size_t BS = 524288;
    const size_t OQ = 0, OKV = 65536, OP = 196608, OM1 = 262144, OM2 = 393216;

    dim3 b256(256);

    PrepArgs pa;
    pa.grd2sat = grd2sat; pa.xcur = xcur;
    pa.grd_x = grd_x;     pa.yhat = yhat;
    pa.u = u; pa.perm = perm; pa.chunks = chunks; pa.nchunks = nchunks;
    {
        int base = 0;
        for (int i = 0; i < 2; ++i) {
            int e = 6 * i;
            unsigned short* bt = Bt + i * BS;
            pa.win[e+0] = Wq + i * 65536;    pa.wout[e+0] = bt + OQ;
            pa.wlnw[e+0] = ln_q_w + i * 256; pa.wR[e+0] = 256; pa.wC[e+0] = 256;
            pa.win[e+1] = Wk + i * 65536;    pa.wout[e+1] = bt + OKV;
            pa.wlnw[e+1] = ln_k_w + i * 256; pa.wR[e+1] = 256; pa.wC[e+1] = 256;
            pa.win[e+2] = Wv + i * 65536;    pa.wout[e+2] = bt + OKV + 65536;
            pa.wlnw[e+2] = ln_v_w + i * 256; pa.wR[e+2] = 256; pa.wC[e+2] = 256;
            pa.win[e+3] = Wproj + i * 65536; pa.wout[e+3] = bt + OP;
            pa.wlnw[e+3] = nullptr;          pa.wR[e+3] = 256; pa.wC[e+3] = 256;
            pa.win[e+4] = Wm1 + i * 131072;  pa.wout[e+4] = bt + OM1;
            pa.wlnw[e+4] = ln_pre_w + i * 256; pa.wR[e+4] = 256; pa.wC[e+4] = 512;
            pa.win[e+5] = Wm2 + i * 131072;  pa.wout[e+5] = bt + OM2;
            pa.wlnw[e+5] = nullptr;          pa.wR[e+5] = 512; pa.wC[e+5] = 256;
        }
        for (int e = 0; e < 12; ++e) {
            pa.wbase[e] = base;
            base += (pa.wR[e] >> 5) * (pa.wC[e] >> 5);
        }
        pa.wbase[12] = base;  // 1024
        for (int i = 0; i < 2; ++i) {
            int jb = 5 * i;
            float* bb = biasbuf + i * 1280;
            pa.fW[jb+0] = Wq + i * 65536; pa.flnb[jb+0] = ln_q_b + i * 256;
            pa.fbase[jb+0] = nullptr; pa.fout[jb+0] = bb;
            pa.fN[jb+0] = 256; pa.fwcol[jb+0] = 0; pa.focol[jb+0] = 0;
            pa.fW[jb+1] = Wk + i * 65536; pa.flnb[jb+1] = ln_k_b + i * 256;
            pa.fbase[jb+1] = nullptr; pa.fout[jb+1] = bb + 256;
            pa.fN[jb+1] = 256; pa.fwcol[jb+1] = 0; pa.focol[jb+1] = 0;
            pa.fW[jb+2] = Wv + i * 65536; pa.flnb[jb+2] = ln_v_b + i * 256;
            pa.fbase[jb+2] = nullptr; pa.fout[jb+2] = bb + 256;
            pa.fN[jb+2] = 256; pa.fwcol[jb+2] = 0; pa.focol[jb+2] = 256;
            pa.fW[jb+3] = Wm1 + i * 131072; pa.flnb[jb+3] = ln_pre_b + i * 256;
            pa.fbase[jb+3] = bm1 + i * 512; pa.fout[jb+3] = bb + 768;
            pa.fN[jb+3] = 512; pa.fwcol[jb+3] = 0; pa.focol[jb+3] = 0;
            pa.fW[jb+4] = Wm1 + i * 131072; pa.flnb[jb+4] = ln_pre_b + i * 256;
            pa.fbase[jb+4] = bm1 + i * 512; pa.fout[jb+4] = bb + 768;
            pa.fN[jb+4] = 512; pa.fwcol[jb+4] = 256; pa.focol[jb+4] = 256;
        }
    }
    prep_kernel<<<1449, b256, 0, stream>>>(pa);

    // ---- K/V tables for both transformer blocks
    GJ jkv0 = {};
    jkv0.A = yhat; jkv0.Bt = Bt + OKV; jkv0.bias = biasbuf + 256;
    jkv0.out = Ktab0; jkv0.out2 = Vt0; jkv0.K = 256; jkv0.N = 512;
    GJ jkv1 = {};
    jkv1.A = yhat; jkv1.Bt = Bt + BS + OKV; jkv1.bias = biasbuf + 1280 + 256;
    jkv1.out = Ktab1; jkv1.out2 = Vt1; jkv1.K = 256; jkv1.N = 512;
    kv_kernel<<<dim3(128, 16), b256, 0, stream>>>(jkv0, jkv1);

    // ---- mega chunk kernel v4 (512 threads, B-preload)
    MegaArgs ma;
    ma.xcur = xcur; ma.perm = perm; ma.chunks = chunks; ma.nchunks = nchunks;
    ma.xfinal = zq;
    for (int i = 0; i < 2; ++i) {
        const unsigned short* bt = Bt + i * BS;
        ma.Wq[i] = bt + OQ; ma.Wp[i] = bt + OP;
        ma.Wm1[i] = bt + OM1; ma.Wm2[i] = bt + OM2;
        ma.Ktb[i] = i ? Ktab1 : Ktab0; ma.Vtb[i] = i ? Vt1 : Vt0;
        ma.qb[i] = biasbuf + i * 1280;
        ma.m1b[i] = biasbuf + i * 1280 + 768;
        ma.bpj[i] = bproj + i * 256;
        ma.bm2v[i] = bm2 + i * 256;
        ma.pw[i] = ln_pre_w + i * 256;
        ma.pb[i] = ln_pre_b + i * 256;
    }
    ma.aw = ln_post_w; ma.ab = ln_post_b;  // block 0 ln_post for layer-1 LN2
    mega_kernel<<<288, dim3(512), 0, stream>>>(ma);

    out_kernel<<<64, b256, 0, stream>>>(zq, ln_post_w + 256, ln_post_b + 256,
                                        (float*)d_out);
}

// Round 5
// 206.596 us; speedup vs baseline: 1.3936x; 1.0025x over previous
//
#include <hip/hip_runtime.h>
#include <math.h>

// ---------------------------------------------------------------------------
// CrossViewAttention — R9: mega v5 — 1024 threads (16 waves, 4/SIMD),
// 16-col wave GEMM slices, 2 waves/head attention. bf16 yhat for kv.
// B=1, C=256, M=4096, W=128, H=32, BLOCKS=2, HEADS=8, DH=32
// ---------------------------------------------------------------------------

#define C_DIM 256
#define M_DIM 4096
#define W_DIM 128
#define H_DIM 32
#define ATT_SCALE 0.17677669529663687f  // 1/sqrt(32)

typedef __attribute__((ext_vector_type(8))) short short8;
typedef __attribute__((ext_vector_type(4))) short short4v;
typedef __attribute__((ext_vector_type(4))) float floatx4;

__device__ __forceinline__ unsigned short f2bf(float f) {
    unsigned u = __float_as_uint(f);
    unsigned r = (u + 0x7fffu + ((u >> 16) & 1u)) >> 16;
    return (unsigned short)r;
}
__device__ __forceinline__ float gelu_exact(float x) {
    return 0.5f * x * (1.0f + erff(x * 0.70710678118654752f));
}

// ======================= mega prep kernel ==================================
struct PrepArgs {
    const float* grd2sat; float* xcur;
    const float* grd_x;   unsigned short* yhat;   // bf16 now
    const float* u; int* perm; int4* chunks; int* nchunks;
    const float* win[12]; unsigned short* wout[12]; const float* wlnw[12];
    int wR[12], wC[12], wbase[13];
    const float* fW[10]; const float* flnb[10]; const float* fbase[10];
    float* fout[10];
    int fN[10], fwcol[10], focol[10];
};

__global__ __launch_bounds__(256) void prep_kernel(PrepArgs a) {
    __shared__ float smemf[9024];
    int b = blockIdx.x, t = threadIdx.x;
    if (b < 256) {
        float (*tile)[65] = (float(*)[65])smemf;
        int m0 = (b & 63) << 6, c0 = (b >> 6) << 6;
        for (int it = 0; it < 16; ++it) {
            int idx = it * 256 + t;
            int co = idx >> 6, mo = idx & 63;
            tile[co][mo] = a.grd2sat[(size_t)(c0 + co) * M_DIM + m0 + mo];
        }
        __syncthreads();
        for (int it = 0; it < 16; ++it) {
            int idx = it * 256 + t;
            int mo = idx >> 6, co = idx & 63;
            a.xcur[(size_t)(m0 + mo) * C_DIM + c0 + co] = tile[co][mo];
        }
    } else if (b < 384) {
        int idx = b - 256;
        int h = idx & 31, w0 = (idx >> 5) << 5;
        float (*tile)[33] = (float(*)[33])smemf;
        float (*ps)[32] = (float(*)[32])(smemf + 8448);
        float (*pss)[32] = (float(*)[32])(smemf + 8704);
        float* mu_s = smemf + 8960;
        float* rs_s = smemf + 8992;
        int wo = t & 31, cb = t >> 5;
        for (int it = 0; it < 32; ++it) {
            int c = it * 8 + cb;
            tile[c][wo] = a.grd_x[(size_t)c * (H_DIM * W_DIM) + h * W_DIM + w0 + wo];
        }
        __syncthreads();
        {
            int w = t & 31, part = t >> 5;
            float s = 0.f, ss = 0.f;
            for (int c = part * 32; c < part * 32 + 32; ++c) {
                float x = tile[c][w];
                s += x; ss += x * x;
            }
            ps[part][w] = s; pss[part][w] = ss;
        }
        __syncthreads();
        if (t < 32) {
            float s = 0.f, ss = 0.f;
            for (int p = 0; p < 8; ++p) { s += ps[p][t]; ss += pss[p][t]; }
            float mu = s * (1.f / 256.f);
            float var = ss * (1.f / 256.f) - mu * mu;
            mu_s[t] = mu;
            rs_s[t] = rsqrtf(var + 1e-5f);
        }
        __syncthreads();
        for (int jj = 0; jj < 32; ++jj) {
            float mu = mu_s[jj], rs = rs_s[jj];
            a.yhat[((size_t)(w0 + jj) * H_DIM + h) * C_DIM + t] =
                f2bf((tile[t][jj] - mu) * rs);
        }
    } else if (b < 1408) {
        int wI = b - 384;
        int e = 0;
        while (wI >= a.wbase[e + 1]) ++e;
        int tl = wI - a.wbase[e];
        int tilesC = a.wC[e] >> 5;
        int tr = tl / tilesC, tc = tl - tr * tilesC;
        int r0 = tr << 5, c0 = tc << 5;
        const float* in = a.win[e];
        unsigned short* out = a.wout[e];
        const float* lnw = a.wlnw[e];
        int R = a.wR[e], Cc = a.wC[e];
        float (*tile)[33] = (float(*)[33])smemf;
        int rl = t >> 3, cq = (t & 7) << 2;
        float4 v = *(const float4*)&in[(size_t)(r0 + rl) * Cc + c0 + cq];
        if (lnw) {
            float s = lnw[r0 + rl];
            v.x *= s; v.y *= s; v.z *= s; v.w *= s;
        }
        tile[rl][cq + 0] = v.x;
        tile[rl][cq + 1] = v.y;
        tile[rl][cq + 2] = v.z;
        tile[rl][cq + 3] = v.w;
        __syncthreads();
        int cl = t >> 3, rq = (t & 7) << 2;
        ushort4 o;
        o.x = f2bf(tile[rq + 0][cl]);
        o.y = f2bf(tile[rq + 1][cl]);
        o.z = f2bf(tile[rq + 2][cl]);
        o.w = f2bf(tile[rq + 3][cl]);
        *(ushort4*)&out[(size_t)(c0 + cl) * R + r0 + rq] = o;
    } else if (b < 1448) {
        int idx = b - 1408;            // 0..39
        int jj = idx >> 2, part = idx & 3;
        int N = a.fN[jj];
        int c = t & 63, kp = t >> 6;   // 4 k-parts of 64
        int wcol = a.fwcol[jj] + (part << 6) + c;
        const float* W = a.fW[jj];
        const float* lb = a.flnb[jj];
        float s = 0.f;
#pragma unroll 4
        for (int k = kp * 64; k < kp * 64 + 64; ++k)
            s += lb[k] * W[(size_t)k * N + wcol];
        smemf[(kp << 6) + c] = s;
        __syncthreads();
        if (t < 64) {
            float tot = smemf[t] + smemf[64 + t] + smemf[128 + t] + smemf[192 + t];
            int ocol = a.focol[jj] + (part << 6) + t;
            if (a.fbase[jj]) tot += a.fbase[jj][a.fwcol[jj] + (part << 6) + t];
            a.fout[jj][ocol] = tot;
        }
    } else {
        int* hist = (int*)smemf;
        int* cur = (int*)smemf + 128;
        unsigned short* wlb = (unsigned short*)((int*)smemf + 256);
        if (t < 128) hist[t] = 0;
        __syncthreads();
        for (int it = 0; it < 16; ++it) {
            int m = it * 256 + t;
            int wl = (int)floorf(a.u[m]);
            wl = max(0, min(wl, 126));
            wlb[m] = (unsigned short)wl;
            atomicAdd(&hist[wl], 1);
        }
        __syncthreads();
        if (t == 0) {
            int run = 0, nc = 0;
            for (int bkt = 0; bkt < 127; ++bkt) {
                int c = hist[bkt];
                cur[bkt] = run;
                int q0 = run;
                while (c > 0) {
                    int take = min(c, 32);
                    a.chunks[nc] = make_int4(bkt, q0, take, 0);
                    ++nc; q0 += take; c -= take;
                }
                run += hist[bkt];
            }
            *a.nchunks = nc;
        }
        __syncthreads();
        for (int it = 0; it < 16; ++it) {
            int m = it * 256 + t;
            int wl = wlb[m];
            int pos = atomicAdd(&cur[wl], 1);
            a.perm[pos] = m;
        }
    }
}

// ======================= KV GEMM (bf16 A) ==================================
struct GJ {
    const void* A; const unsigned short* Bt;
    const float* bias;
    void* out; unsigned short* out2;
    int K, N;
};

__device__ __forceinline__ void gemm_core_kv(const GJ& j, short (*As)[264],
                                             short (*Bs)[264], int bm, int by) {
    int t = threadIdx.x;
    int bn = by << 6;
    int wv = t >> 6, lane = t & 63;
    int mt = wv & 1, nt0 = (wv >> 1) << 1;
    int quad = lane >> 4, l16 = lane & 15;
    floatx4 acc0 = {0.f, 0.f, 0.f, 0.f};
    floatx4 acc1 = {0.f, 0.f, 0.f, 0.f};
    {
        int ar = t >> 3, cq = (t & 7) << 5;
        const unsigned short* ap =
            (const unsigned short*)j.A + (size_t)(bm + ar) * 256 + cq;
#pragma unroll
        for (int c = 0; c < 4; ++c)
            *(uint4*)&As[ar][cq + (c << 3)] = *(const uint4*)(ap + (c << 3));
    }
    {
        int br = t >> 2, cq2 = (t & 3) << 3;
        const unsigned short* bp = j.Bt + (size_t)(bn + br) * 256 + cq2;
#pragma unroll
        for (int g = 0; g < 8; ++g)
            *(short8*)&Bs[br][cq2 + g * 32] = *(const short8*)(bp + g * 32);
    }
    __syncthreads();
#pragma unroll
    for (int k0 = 0; k0 < 8; ++k0) {
        short8 aa = *(const short8*)&As[(mt << 4) + l16][(k0 << 5) + (quad << 3)];
        short8 b0 = *(const short8*)&Bs[(nt0 << 4) + l16][(k0 << 5) + (quad << 3)];
        short8 b1 =
            *(const short8*)&Bs[((nt0 + 1) << 4) + l16][(k0 << 5) + (quad << 3)];
        acc0 = __builtin_amdgcn_mfma_f32_16x16x32_bf16(aa, b0, acc0, 0, 0, 0);
        acc1 = __builtin_amdgcn_mfma_f32_16x16x32_bf16(aa, b1, acc1, 0, 0, 0);
    }
#pragma unroll
    for (int jj = 0; jj < 2; ++jj) {
        const floatx4 accv = jj ? acc1 : acc0;
        int col = bn + ((nt0 + jj) << 4) + l16;
        float bv = j.bias[col];
#pragma unroll
        for (int r = 0; r < 4; ++r) {
            int row = bm + (mt << 4) + (quad << 2) + r;
            float v = accv[r] + bv;
            if (col < 256)
                ((unsigned short*)j.out)[(size_t)row * 256 + col] = f2bf(v);
            else
                j.out2[(size_t)(col - 256) * M_DIM + row] = f2bf(v);
        }
    }
}

__global__ __launch_bounds__(256) void kv_kernel(GJ j0, GJ j1) {
    __shared__ short As[32][264];
    __shared__ short Bs[64][264];
    int bm = blockIdx.x << 5;
    if ((int)blockIdx.y < 8)
        gemm_core_kv(j0, As, Bs, bm, blockIdx.y);
    else
        gemm_core_kv(j1, As, Bs, bm, blockIdx.y - 8);
}

// ======================= mega chunk kernel v5 (1024 thr) ===================
struct MegaArgs {
    const float* xcur;
    const int* perm; const int4* chunks; const int* nchunks;
    float* xfinal;
    const unsigned short* Wq[2]; const unsigned short* Wp[2];
    const unsigned short* Wm1[2]; const unsigned short* Wm2[2];
    const unsigned short* Ktb[2]; const unsigned short* Vtb[2];
    const float* qb[2]; const float* m1b[2];
    const float* bpj[2]; const float* bm2v[2];
    const float* pw[2]; const float* pb[2];
    const float* aw; const float* ab;  // ln_post[0] for layer-1 LN2
};

struct BPre8 { short8 b[8]; };     // 8 k0-frags, one 16-col tile (32 VGPR)
struct BPre16 { short8 b[8][2]; }; // two 16-col tiles (64 VGPR)

__device__ __forceinline__ void preload8(const unsigned short* Bt, int Ks,
                                         int koff, int colw, int l16, int quad,
                                         BPre8& P) {
    const unsigned short* bp = Bt + (size_t)(colw + l16) * Ks + koff + (quad << 3);
#pragma unroll
    for (int k0 = 0; k0 < 8; ++k0) P.b[k0] = *(const short8*)(bp + (k0 << 5));
}
__device__ __forceinline__ void preload16(const unsigned short* Bt, int Ks,
                                          int colw, int l16, int quad, BPre16& P) {
    const unsigned short* bp = Bt + (size_t)(colw + l16) * Ks + (quad << 3);
#pragma unroll
    for (int k0 = 0; k0 < 8; ++k0)
#pragma unroll
        for (int nt = 0; nt < 2; ++nt)
            P.b[k0][nt] = *(const short8*)(bp + (size_t)(nt << 4) * Ks + (k0 << 5));
}

// 32 rows (2 m-halves) x 16 cols: acc[2]
__device__ __forceinline__ void mfma16(const short* As, int lda, const BPre8& P,
                                       int l16, int quad, floatx4 acc[2]) {
    const short* ap = As + (size_t)l16 * lda + (quad << 3);
#pragma unroll
    for (int k0 = 0; k0 < 8; ++k0) {
        short8 a0 = *(const short8*)(ap + (k0 << 5));
        short8 a1 = *(const short8*)(ap + (size_t)16 * lda + (k0 << 5));
        acc[0] = __builtin_amdgcn_mfma_f32_16x16x32_bf16(a0, P.b[k0], acc[0], 0, 0, 0);
        acc[1] = __builtin_amdgcn_mfma_f32_16x16x32_bf16(a1, P.b[k0], acc[1], 0, 0, 0);
    }
}
// 32 rows x 32 cols (m1): acc[2][2]
__device__ __forceinline__ void mfma16x2(const short* As, int lda, const BPre16& P,
                                         int l16, int quad, floatx4 acc[2][2]) {
    const short* ap = As + (size_t)l16 * lda + (quad << 3);
#pragma unroll
    for (int k0 = 0; k0 < 8; ++k0) {
        short8 a0 = *(const short8*)(ap + (k0 << 5));
        short8 a1 = *(const short8*)(ap + (size_t)16 * lda + (k0 << 5));
        acc[0][0] = __builtin_amdgcn_mfma_f32_16x16x32_bf16(a0, P.b[k0][0], acc[0][0], 0, 0, 0);
        acc[0][1] = __builtin_amdgcn_mfma_f32_16x16x32_bf16(a0, P.b[k0][1], acc[0][1], 0, 0, 0);
        acc[1][0] = __builtin_amdgcn_mfma_f32_16x16x32_bf16(a1, P.b[k0][0], acc[1][0], 0, 0, 0);
        acc[1][1] = __builtin_amdgcn_mfma_f32_16x16x32_bf16(a1, P.b[k0][1], acc[1][1], 0, 0, 0);
    }
}

// LDS layout (bytes) — same as v4:
//  [0,      16896)  XH short[32][264]  (stage1->Q) / HH0 (m1 cols 0-255)
//  [16896,  33792)  QR short[32][264]  (Q->attn)   / HH1 (m1 cols 256-511)
//  [33792,  50688)  ZH short[32][264]  (LNz->m1)
//  [50688,  67584)  AR short[32][264]  (attn->proj)
//  [67584, 100864)  Zf float[32][260]  (proj z; residual; x' in-place)
//  [100864,137728)  PB short[16][16][72] (per-wave softmax P slot)
//  [137728,137856)  gperm int[32]
__global__ __launch_bounds__(1024) void mega_kernel(MegaArgs a) {
    __shared__ __align__(16) char smem[137856];
    short (*XH)[264] = (short(*)[264])(smem);
    short (*QR)[264] = (short(*)[264])(smem + 16896);
    short (*ZH)[264] = (short(*)[264])(smem + 33792);
    short (*AR)[264] = (short(*)[264])(smem + 50688);
    float (*Zf)[260] = (float(*)[260])(smem + 67584);
    short (*PB)[16][72] = (short(*)[16][72])(smem + 100864);
    int* gp = (int*)(smem + 137728);

    if ((int)blockIdx.x >= *a.nchunks) return;
    int4 cd = a.chunks[blockIdx.x];
    int wl = cd.x, qstart = cd.y, qcnt = cd.z;
    int t = threadIdx.x;
    if (t < 32) gp[t] = (t < qcnt) ? a.perm[qstart + t] : a.perm[qstart];
    __syncthreads();

    int wv = t >> 6, lane = t & 63, quad = lane >> 4, l16 = lane & 15;
    int colw = wv << 4;                     // 16-col GEMM slice
    int colw2 = wv << 5;                    // 32-col m1 slice
    int r32 = t >> 5, c8 = (t & 31) << 3;   // LN map: 32 rows, 8 floats

#pragma unroll 1
    for (int l = 0; l < 2; ++l) {
        // ---------------- stage1: XH = LN(x) (l=1: LN->ln_post0 affine->LN)
        BPre8 Pq;
        preload8(a.Wq[l], 256, 0, colw, l16, quad, Pq);
        {
            float4 v[2];
            if (l == 0) {
                const float* xp = a.xcur + (size_t)gp[r32] * 256 + c8;
                v[0] = *(const float4*)(xp);
                v[1] = *(const float4*)(xp + 4);
            } else {
                v[0] = *(const float4*)&Zf[r32][c8];
                v[1] = *(const float4*)&Zf[r32][c8 + 4];
            }
            float s = 0.f, ss = 0.f;
#pragma unroll
            for (int g = 0; g < 2; ++g) {
                s += v[g].x + v[g].y + v[g].z + v[g].w;
                ss += v[g].x * v[g].x + v[g].y * v[g].y + v[g].z * v[g].z +
                      v[g].w * v[g].w;
            }
#pragma unroll
            for (int o = 1; o < 32; o <<= 1) {
                s += __shfl_xor(s, o, 64);
                ss += __shfl_xor(ss, o, 64);
            }
            float mu = s * (1.f / 256.f);
            float rs = rsqrtf(ss * (1.f / 256.f) - mu * mu + 1e-5f);
#pragma unroll
            for (int g = 0; g < 2; ++g) {
                v[g].x = (v[g].x - mu) * rs;
                v[g].y = (v[g].y - mu) * rs;
                v[g].z = (v[g].z - mu) * rs;
                v[g].w = (v[g].w - mu) * rs;
            }
            if (l == 1) {
                float s2 = 0.f, ss2 = 0.f;
#pragma unroll
                for (int g = 0; g < 2; ++g) {
                    float4 w4 = *(const float4*)&a.aw[c8 + (g << 2)];
                    float4 b4 = *(const float4*)&a.ab[c8 + (g << 2)];
                    v[g].x = v[g].x * w4.x + b4.x;
                    v[g].y = v[g].y * w4.y + b4.y;
                    v[g].z = v[g].z * w4.z + b4.z;
                    v[g].w = v[g].w * w4.w + b4.w;
                    s2 += v[g].x + v[g].y + v[g].z + v[g].w;
                    ss2 += v[g].x * v[g].x + v[g].y * v[g].y + v[g].z * v[g].z +
                           v[g].w * v[g].w;
                }
#pragma unroll
                for (int o = 1; o < 32; o <<= 1) {
                    s2 += __shfl_xor(s2, o, 64);
                    ss2 += __shfl_xor(ss2, o, 64);
                }
                float mu2 = s2 * (1.f / 256.f);
                float rs2 = rsqrtf(ss2 * (1.f / 256.f) - mu2 * mu2 + 1e-5f);
#pragma unroll
                for (int g = 0; g < 2; ++g) {
                    v[g].x = (v[g].x - mu2) * rs2;
                    v[g].y = (v[g].y - mu2) * rs2;
                    v[g].z = (v[g].z - mu2) * rs2;
                    v[g].w = (v[g].w - mu2) * rs2;
                }
            }
#pragma unroll
            for (int g = 0; g < 2; ++g) {
                short4v o;
                o[0] = (short)f2bf(v[g].x);
                o[1] = (short)f2bf(v[g].y);
                o[2] = (short)f2bf(v[g].z);
                o[3] = (short)f2bf(v[g].w);
                *(short4v*)&XH[r32][c8 + (g << 2)] = o;
            }
        }
        __syncthreads();

        // ---------------- Q: QR = XH @ Wq'^T + qb (16 cols/wave)
        // K/V fragments for attention issued here (hidden under Q MFMAs)
        short8 kb[4], vfrag[2][2];
        {
            const unsigned short* Kt = a.Ktb[l];
            const unsigned short* Vt = a.Vtb[l];
            int h = wv >> 1;
#pragma unroll
            for (int nt = 0; nt < 4; ++nt)
                kb[nt] = *(const short8*)(
                    Kt + (size_t)((wl << 5) + (nt << 4) + l16) * 256 +
                    (h << 5) + (quad << 3));
#pragma unroll
            for (int ks = 0; ks < 2; ++ks)
#pragma unroll
                for (int dt = 0; dt < 2; ++dt)
                    vfrag[ks][dt] = *(const short8*)(
                        Vt + (size_t)((h << 5) + (dt << 4) + l16) * M_DIM +
                        (wl << 5) + (ks << 5) + (quad << 3));
        }
        {
            floatx4 acc[2];
            acc[0] = (floatx4){0.f, 0.f, 0.f, 0.f};
            acc[1] = (floatx4){0.f, 0.f, 0.f, 0.f};
            mfma16((const short*)XH, 264, Pq, l16, quad, acc);
            int col = colw + l16;
            float bv = a.qb[l][col];
#pragma unroll
            for (int mi = 0; mi < 2; ++mi)
#pragma unroll
                for (int r = 0; r < 4; ++r)
                    QR[(mi << 4) + (quad << 2) + r][col] =
                        (short)f2bf(acc[mi][r] + bv);
        }
        __syncthreads();

        // ---------------- attention: 2 waves/head (row halves), in-wave SM
        BPre8 Pp;
        {
            int h = wv >> 1, mh = wv & 1;
            short8 aq = *(const short8*)&QR[(mh << 4) + l16][(h << 5) + (quad << 3)];
            floatx4 c[4];
#pragma unroll
            for (int nt = 0; nt < 4; ++nt) {
                floatx4 z = {0.f, 0.f, 0.f, 0.f};
                c[nt] = __builtin_amdgcn_mfma_f32_16x16x32_bf16(aq, kb[nt], z, 0, 0, 0);
            }
#pragma unroll
            for (int nt = 0; nt < 4; ++nt) {
                floatx4 e;
#pragma unroll
                for (int r = 0; r < 4; ++r) e[r] = __expf(c[nt][r] * ATT_SCALE);
                c[nt] = e;
            }
            floatx4 s4 = c[0] + c[1] + c[2] + c[3];
            floatx4 ri;
#pragma unroll
            for (int r = 0; r < 4; ++r) {
                float s = s4[r];
                s += __shfl_xor(s, 1, 64);
                s += __shfl_xor(s, 2, 64);
                s += __shfl_xor(s, 4, 64);
                s += __shfl_xor(s, 8, 64);
                ri[r] = 1.f / s;
            }
#pragma unroll
            for (int nt = 0; nt < 4; ++nt)
#pragma unroll
                for (int r = 0; r < 4; ++r)
                    PB[wv][(quad << 2) + r][(nt << 4) + l16] =
                        (short)f2bf(c[nt][r] * ri[r]);
            __threadfence_block();
            preload8(a.Wp[l], 256, 0, colw, l16, quad, Pp);  // hidden under PV
            floatx4 o[2];
            o[0] = (floatx4){0.f, 0.f, 0.f, 0.f};
            o[1] = (floatx4){0.f, 0.f, 0.f, 0.f};
#pragma unroll
            for (int ks = 0; ks < 2; ++ks) {
                short8 pa = *(const short8*)&PB[wv][l16][(ks << 5) + (quad << 3)];
#pragma unroll
                for (int dt = 0; dt < 2; ++dt)
                    o[dt] = __builtin_amdgcn_mfma_f32_16x16x32_bf16(
                        pa, vfrag[ks][dt], o[dt], 0, 0, 0);
            }
#pragma unroll
            for (int dt = 0; dt < 2; ++dt)
#pragma unroll
                for (int r = 0; r < 4; ++r)
                    AR[(mh << 4) + (quad << 2) + r]
                      [(h << 5) + (dt << 4) + l16] = (short)f2bf(o[dt][r]);
        }
        __syncthreads();

        // ---------------- proj: Zf = AR @ Wp'^T + bproj (fp32)
        {
            floatx4 acc[2];
            acc[0] = (floatx4){0.f, 0.f, 0.f, 0.f};
            acc[1] = (floatx4){0.f, 0.f, 0.f, 0.f};
            mfma16((const short*)AR, 264, Pp, l16, quad, acc);
            int col = colw + l16;
            float bv = a.bpj[l][col];
#pragma unroll
            for (int mi = 0; mi < 2; ++mi)
#pragma unroll
                for (int r = 0; r < 4; ++r)
                    Zf[(mi << 4) + (quad << 2) + r][col] = acc[mi][r] + bv;
        }
        __syncthreads();

        // ---------------- LNz: ZH = bf16(LN(Z)); Zf <- LN(Z)*pw+pb
        BPre16 Pm1;
        preload16(a.Wm1[l], 256, colw2, l16, quad, Pm1);
        {
            const float* pw = a.pw[l];
            const float* pb = a.pb[l];
            float4 v[2];
            v[0] = *(const float4*)&Zf[r32][c8];
            v[1] = *(const float4*)&Zf[r32][c8 + 4];
            float s = 0.f, ss = 0.f;
#pragma unroll
            for (int g = 0; g < 2; ++g) {
                s += v[g].x + v[g].y + v[g].z + v[g].w;
                ss += v[g].x * v[g].x + v[g].y * v[g].y + v[g].z * v[g].z +
                      v[g].w * v[g].w;
            }
#pragma unroll
            for (int o = 1; o < 32; o <<= 1) {
                s += __shfl_xor(s, o, 64);
                ss += __shfl_xor(ss, o, 64);
            }
            float mu = s * (1.f / 256.f);
            float rs = rsqrtf(ss * (1.f / 256.f) - mu * mu + 1e-5f);
#pragma unroll
            for (int g = 0; g < 2; ++g) {
                float4 z;
                z.x = (v[g].x - mu) * rs;
                z.y = (v[g].y - mu) * rs;
                z.z = (v[g].z - mu) * rs;
                z.w = (v[g].w - mu) * rs;
                short4v o;
                o[0] = (short)f2bf(z.x);
                o[1] = (short)f2bf(z.y);
                o[2] = (short)f2bf(z.z);
                o[3] = (short)f2bf(z.w);
                *(short4v*)&ZH[r32][c8 + (g << 2)] = o;
                float4 w4 = *(const float4*)&pw[c8 + (g << 2)];
                float4 b4 = *(const float4*)&pb[c8 + (g << 2)];
                float4 za;
                za.x = z.x * w4.x + b4.x;
                za.y = z.y * w4.y + b4.y;
                za.z = z.z * w4.z + b4.z;
                za.w = z.w * w4.w + b4.w;
                *(float4*)&Zf[r32][c8 + (g << 2)] = za;
            }
        }
        __syncthreads();

        // ---------------- m1: gelu(ZH @ Wm1'^T + m1b) -> HH0(XH)/HH1(QR)
        BPre8 Pm2a;
        {
            floatx4 acc2[2][2];
            acc2[0][0] = (floatx4){0.f, 0.f, 0.f, 0.f};
            acc2[0][1] = (floatx4){0.f, 0.f, 0.f, 0.f};
            acc2[1][0] = (floatx4){0.f, 0.f, 0.f, 0.f};
            acc2[1][1] = (floatx4){0.f, 0.f, 0.f, 0.f};
            mfma16x2((const short*)ZH, 264, Pm1, l16, quad, acc2);
            preload8(a.Wm2[l], 512, 0, colw, l16, quad, Pm2a);
            const float* m1b = a.m1b[l];
#pragma unroll
            for (int nt = 0; nt < 2; ++nt) {
                int col = colw2 + (nt << 4) + l16;
                float bv = m1b[col];
                short (*H)[264] = (col >> 8) ? QR : XH;
                int lc = col & 255;
#pragma unroll
                for (int mi = 0; mi < 2; ++mi)
#pragma unroll
                    for (int r = 0; r < 4; ++r)
                        H[(mi << 4) + (quad << 2) + r][lc] =
                            (short)f2bf(gelu_exact(acc2[mi][nt][r] + bv));
            }
        }
        __syncthreads();

        // ---------------- m2: x' = HH @ Wm2'^T + bm2 + Zf (K=512)
        {
            floatx4 macc[2];
            macc[0] = (floatx4){0.f, 0.f, 0.f, 0.f};
            macc[1] = (floatx4){0.f, 0.f, 0.f, 0.f};
            mfma16((const short*)XH, 264, Pm2a, l16, quad, macc);
            BPre8 Pm2b;
            preload8(a.Wm2[l], 512, 256, colw, l16, quad, Pm2b);
            mfma16((const short*)QR, 264, Pm2b, l16, quad, macc);
            int col = colw + l16;
            float bv = a.bm2v[l][col];
#pragma unroll
            for (int mi = 0; mi < 2; ++mi)
#pragma unroll
                for (int r = 0; r < 4; ++r) {
                    int row = (mi << 4) + (quad << 2) + r;
                    float v = macc[mi][r] + bv + Zf[row][col];
                    if (l == 0) {
                        Zf[row][col] = v;
                    } else if (row < qcnt) {
                        a.xfinal[(size_t)gp[row] * 256 + col] = v;
                    }
                }
        }
        __syncthreads();
    }
}

// ======================= final: LN_post + L2 norm + transpose ==============
__global__ __launch_bounds__(256) void out_kernel(const float* __restrict__ X,
                                                  const float* __restrict__ w,
                                                  const float* __restrict__ b,
                                                  float* __restrict__ out) {
    __shared__ float tile[32][261];
    int t = threadIdx.x;
    int mo = t >> 3, q = t & 7;   // 32 rows, 8 threads/row, 32 cols each
    int m0 = blockIdx.x << 5;
    const float* p = X + (size_t)(m0 + mo) * C_DIM + (q << 5);
    float4 v[8];
    float s = 0.f, ss = 0.f;
#pragma unroll
    for (int c = 0; c < 8; ++c) {
        v[c] = *(const float4*)(p + c * 4);
        s += v[c].x + v[c].y + v[c].z + v[c].w;
        ss += v[c].x * v[c].x + v[c].y * v[c].y + v[c].z * v[c].z + v[c].w * v[c].w;
    }
    s += __shfl_xor(s, 1, 64); s += __shfl_xor(s, 2, 64); s += __shfl_xor(s, 4, 64);
    ss += __shfl_xor(ss, 1, 64); ss += __shfl_xor(ss, 2, 64); ss += __shfl_xor(ss, 4, 64);
    float mu = s * (1.f / 256.f);
    float rs = rsqrtf(ss * (1.f / 256.f) - mu * mu + 1e-5f);
    float ss2 = 0.f;
#pragma unroll
    for (int c = 0; c < 8; ++c) {
        float4 w4 = *(const float4*)&w[(q << 5) + c * 4];
        float4 b4 = *(const float4*)&b[(q << 5) + c * 4];
        v[c].x = (v[c].x - mu) * rs * w4.x + b4.x;
        v[c].y = (v[c].y - mu) * rs * w4.y + b4.y;
        v[c].z = (v[c].z - mu) * rs * w4.z + b4.z;
        v[c].w = (v[c].w - mu) * rs * w4.w + b4.w;
        ss2 += v[c].x * v[c].x + v[c].y * v[c].y + v[c].z * v[c].z + v[c].w * v[c].w;
    }
    ss2 += __shfl_xor(ss2, 1, 64); ss2 += __shfl_xor(ss2, 2, 64); ss2 += __shfl_xor(ss2, 4, 64);
    float sc = 1.f / fmaxf(sqrtf(ss2), 1e-12f);
#pragma unroll
    for (int c = 0; c < 8; ++c) {
        tile[mo][(q << 5) + c * 4 + 0] = v[c].x * sc;
        tile[mo][(q << 5) + c * 4 + 1] = v[c].y * sc;
        tile[mo][(q << 5) + c * 4 + 2] = v[c].z * sc;
        tile[mo][(q << 5) + c * 4 + 3] = v[c].w * sc;
    }
    __syncthreads();
#pragma unroll 1
    for (int it = 0; it < 32; ++it) {
        int idx = it * 256 + t;
        int c = idx >> 5, m = idx & 31;
        out[(size_t)c * M_DIM + m0 + m] = tile[m][c];
    }
}

// ---------------------------------------------------------------------------
extern "C" void kernel_launch(void* const* d_in, const int* in_sizes, int n_in,
                              void* d_out, int out_size, void* d_ws, size_t ws_size,
                              hipStream_t stream) {
    const float* grd2sat = (const float*)d_in[0];
    const float* grd_x   = (const float*)d_in[1];
    const float* u       = (const float*)d_in[2];
    const float* ln_q_w  = (const float*)d_in[3];
    const float* ln_q_b  = (const float*)d_in[4];
    const float* ln_k_w  = (const float*)d_in[5];
    const float* ln_k_b  = (const float*)d_in[6];
    const float* ln_v_w  = (const float*)d_in[7];
    const float* ln_v_b  = (const float*)d_in[8];
    const float* Wq      = (const float*)d_in[9];
    const float* Wk      = (const float*)d_in[10];
    const float* Wv      = (const float*)d_in[11];
    const float* Wproj   = (const float*)d_in[12];
    const float* bproj   = (const float*)d_in[13];
    const float* ln_pre_w = (const float*)d_in[14];
    const float* ln_pre_b = (const float*)d_in[15];
    const float* Wm1     = (const float*)d_in[16];
    const float* bm1     = (const float*)d_in[17];
    const float* Wm2     = (const float*)d_in[18];
    const float* bm2     = (const float*)d_in[19];
    const float* ln_post_w = (const float*)d_in[20];
    const float* ln_post_b = (const float*)d_in[21];

    float* ws   = (float*)d_ws;
    unsigned short* yhat = (unsigned short*)ws;  // 2 MB (bf16 now)
    float* xcur = ws + 1048576;              // 4 MB
    float* zq   = ws + 2097152;              // 4 MB (xfinal)
    unsigned short* Ktab0 = (unsigned short*)(ws + 6291456); // 2 MB
    unsigned short* Vt0   = (unsigned short*)(ws + 6815744); // 2 MB
    unsigned short* Ktab1 = (unsigned short*)(ws + 7340032); // 2 MB
    unsigned short* Vt1   = (unsigned short*)(ws + 7864320); // 2 MB
    unsigned short* Bt    = (unsigned short*)(ws + 8388608); // 2 MB (both blocks)
    float* biasbuf = ws + 8912896;           // 2560 floats
    int*  perm    = (int*)(ws + 8915456);    // 4096 ints
    int4* chunks  = (int4*)(ws + 8919552);   // 512 int4
    int*  nchunks = (int*)(ws + 8921600);
    const size_t BS = 524288;
    const size_t OQ = 0, OKV = 65536, OP = 196608, OM1 = 262144, OM2 = 393216;

    dim3 b256(256);

    PrepArgs pa;
    pa.grd2sat = grd2sat; pa.xcur = xcur;
    pa.grd_x = grd_x;     pa.yhat = yhat;
    pa.u = u; pa.perm = perm; pa.chunks = chunks; pa.nchunks = nchunks;
    {
        int base = 0;
        for (int i = 0; i < 2; ++i) {
            int e = 6 * i;
            unsigned short* bt = Bt + i * BS;
            pa.win[e+0] = Wq + i * 65536;    pa.wout[e+0] = bt + OQ;
            pa.wlnw[e+0] = ln_q_w + i * 256; pa.wR[e+0] = 256; pa.wC[e+0] = 256;
            pa.win[e+1] = Wk + i * 65536;    pa.wout[e+1] = bt + OKV;
            pa.wlnw[e+1] = ln_k_w + i * 256; pa.wR[e+1] = 256; pa.wC[e+1] = 256;
            pa.win[e+2] = Wv + i * 65536;    pa.wout[e+2] = bt + OKV + 65536;
            pa.wlnw[e+2] = ln_v_w + i * 256; pa.wR[e+2] = 256; pa.wC[e+2] = 256;
            pa.win[e+3] = Wproj + i * 65536; pa.wout[e+3] = bt + OP;
            pa.wlnw[e+3] = nullptr;          pa.wR[e+3] = 256; pa.wC[e+3] = 256;
            pa.win[e+4] = Wm1 + i * 131072;  pa.wout[e+4] = bt + OM1;
            pa.wlnw[e+4] = ln_pre_w + i * 256; pa.wR[e+4] = 256; pa.wC[e+4] = 512;
            pa.win[e+5] = Wm2 + i * 131072;  pa.wout[e+5] = bt + OM2;
            pa.wlnw[e+5] = nullptr;          pa.wR[e+5] = 512; pa.wC[e+5] = 256;
        }
        for (int e = 0; e < 12; ++e) {
            pa.wbase[e] = base;
            base += (pa.wR[e] >> 5) * (pa.wC[e] >> 5);
        }
        pa.wbase[12] = base;  // 1024
        for (int i = 0; i < 2; ++i) {
            int jb = 5 * i;
            float* bb = biasbuf + i * 1280;
            pa.fW[jb+0] = Wq + i * 65536; pa.flnb[jb+0] = ln_q_b + i * 256;
            pa.fbase[jb+0] = nullptr; pa.fout[jb+0] = bb;
            pa.fN[jb+0] = 256; pa.fwcol[jb+0] = 0; pa.focol[jb+0] = 0;
            pa.fW[jb+1] = Wk + i * 65536; pa.flnb[jb+1] = ln_k_b + i * 256;
            pa.fbase[jb+1] = nullptr; pa.fout[jb+1] = bb + 256;
            pa.fN[jb+1] = 256; pa.fwcol[jb+1] = 0; pa.focol[jb+1] = 0;
            pa.fW[jb+2] = Wv + i * 65536; pa.flnb[jb+2] = ln_v_b + i * 256;
            pa.fbase[jb+2] = nullptr; pa.fout[jb+2] = bb + 256;
            pa.fN[jb+2] = 256; pa.fwcol[jb+2] = 0; pa.focol[jb+2] = 256;
            pa.fW[jb+3] = Wm1 + i * 131072; pa.flnb[jb+3] = ln_pre_b + i * 256;
            pa.fbase[jb+3] = bm1 + i * 512; pa.fout[jb+3] = bb + 768;
            pa.fN[jb+3] = 512; pa.fwcol[jb+3] = 0; pa.focol[jb+3] = 0;
            pa.fW[jb+4] = Wm1 + i * 131072; pa.flnb[jb+4] = ln_pre_b + i * 256;
            pa.fbase[jb+4] = bm1 + i * 512; pa.fout[jb+4] = bb + 768;
            pa.fN[jb+4] = 512; pa.fwcol[jb+4] = 256; pa.focol[jb+4] = 256;
        }
    }
    prep_kernel<<<1449, b256, 0, stream>>>(pa);

    // ---- K/V tables for both transformer blocks
    GJ jkv0 = {};
    jkv0.A = yhat; jkv0.Bt = Bt + OKV; jkv0.bias = biasbuf + 256;
    jkv0.out = Ktab0; jkv0.out2 = Vt0; jkv0.K = 256; jkv0.N = 512;
    GJ jkv1 = {};
    jkv1.A = yhat; jkv1.Bt = Bt + BS + OKV; jkv1.bias = biasbuf + 1280 + 256;
    jkv1.out = Ktab1; jkv1.out2 = Vt1; jkv1.K = 256; jkv1.N = 512;
    kv_kernel<<<dim3(128, 16), b256, 0, stream>>>(jkv0, jkv1);

    // ---- mega chunk kernel v5 (1024 threads)
    MegaArgs ma;
    ma.xcur = xcur; ma.perm = perm; ma.chunks = chunks; ma.nchunks = nchunks;
    ma.xfinal = zq;
    for (int i = 0; i < 2; ++i) {
        const unsigned short* bt = Bt + i * BS;
        ma.Wq[i] = bt + OQ; ma.Wp[i] = bt + OP;
        ma.Wm1[i] = bt + OM1; ma.Wm2[i] = bt + OM2;
        ma.Ktb[i] = i ? Ktab1 : Ktab0; ma.Vtb[i] = i ? Vt1 : Vt0;
        ma.qb[i] = biasbuf + i * 1280;
        ma.m1b[i] = biasbuf + i * 1280 + 768;
        ma.bpj[i] = bproj + i * 256;
        ma.bm2v[i] = bm2 + i * 256;
        ma.pw[i] = ln_pre_w + i * 256;
        ma.pb[i] = ln_pre_b + i * 256;
    }
    ma.aw = ln_post_w; ma.ab = ln_post_b;  // block 0 ln_post for layer-1 LN2
    mega_kernel<<<288, dim3(1024), 0, stream>>>(ma);

    out_kernel<<<128, b256, 0, stream>>>(zq, ln_post_w + 256, ln_post_b + 256,
                                         (float*)d_out);
}